// Round 1
// baseline (1182.538 us; speedup 1.0000x reference)
//
#include <hip/hip_runtime.h>
#include <math.h>

#define HWp 4096
#define Cp 256
#define Lp 2048
#define Np 3
#define Bp 8

#define OUT_FEAT_N 8388608      // 8*256*4096
#define OUT_BASE_OFF 8388608
#define OUT_REF_OFF 8404992     // + 8*2048

// ws offsets (float units)
#define WS_AT    0                        // 4,194,304 floats
#define WS_BT    4194304                  // 12,582,912 floats
#define WS_NORMA 16777216                 // 16,384
#define WS_PVAL  16793600                 // 196,608
#define WS_PIDX  16990208                 // 196,608 (ints)
#define WS_BEST  17186816                 // 49,152 (ints)
#define WS_CAND2 17235968                 // 49,152 (ints)
#define WS_COUNT 17285120                 // 1 (int)
#define WS_LIST  17285121                 // 49,152 (ints)

__global__ void copy_feat_kernel(const float4* __restrict__ src, float4* __restrict__ dst, int n4){
    int i = blockIdx.x * blockDim.x + threadIdx.x;
    int stride = gridDim.x * blockDim.x;
    for (; i < n4; i += stride) dst[i] = src[i];
}

// Gather selected columns, l2-normalize over c, store k-major: dstT[group][c][L]
__global__ void gather_norm_kernel(const float* __restrict__ src,
                                   const int* __restrict__ idx,
                                   const int* __restrict__ pindex,
                                   float* __restrict__ dstT,
                                   float* __restrict__ normOut,
                                   int nGroups, int isRef)
{
    int tile = blockIdx.x & 127;          // L/16 tiles
    int bg = blockIdx.x >> 7;
    int g = bg % nGroups, b = bg / nGroups;
    const float* sbase;
    if (isRef){
        int iv = *pindex;
        int rn = (g < iv) ? g : g + 1;
        sbase = src + ((size_t)(b*4 + rn)) * Cp * HWp;
    } else {
        sbase = src + ((size_t)b) * Cp * HWp;
    }
    const int* ibase = idx + ((size_t)bg) * Lp;
    float* dbase = dstT + ((size_t)bg) * Cp * Lp;
    __shared__ float tb[16][Cp + 1];
    __shared__ float wsum[4];
    int tid = threadIdx.x;                 // = c
    int lane = tid & 63, wid = tid >> 6;
    int l0 = tile * 16;
    for (int j = 0; j < 16; j++){
        int pos = ibase[l0 + j];
        float x = sbase[(size_t)tid * HWp + pos];
        float ss = x * x;
        #pragma unroll
        for (int off = 32; off; off >>= 1) ss += __shfl_xor(ss, off, 64);
        if (lane == 0) wsum[wid] = ss;
        __syncthreads();
        float denom = fmaxf(sqrtf(wsum[0] + wsum[1] + wsum[2] + wsum[3]), 1e-12f);
        tb[j][tid] = x / denom;
        if (normOut && tid == 0) normOut[(size_t)b * Lp + l0 + j] = denom;
        __syncthreads();
    }
    float* drow = dbase + (size_t)tid * Lp + l0;
    #pragma unroll
    for (int u = 0; u < 4; u++){
        float4 v = make_float4(tb[u*4+0][tid], tb[u*4+1][tid], tb[u*4+2][tid], tb[u*4+3][tid]);
        *(float4*)&drow[u*4] = v;
    }
}

// C = A_rows . B_cols (dot over c), fused per-row top-2 over columns.
// Block: 128 rows x 1024 cols (half), BK=32, 256 thr, 8x8 micro-tile.
__global__ __launch_bounds__(256) void gemm_argmax_kernel(
    const float* __restrict__ A_T, const float* __restrict__ B_T,
    float* __restrict__ pval, int* __restrict__ pidx)
{
    int t = blockIdx.x;
    int half = t & 1;
    int rt = (t >> 1) & 15;
    int bn = t >> 5;                       // b*3+n
    int b = bn / 3;
    const float* Ab = A_T + (size_t)b  * Cp * Lp;
    const float* Bb = B_T + (size_t)bn * Cp * Lp;
    int l0 = rt * 128;
    int m00 = half * 1024;
    __shared__ float Al[32][132];
    __shared__ float Bl[32][132];
    int tid = threadIdx.x;
    int tx = tid & 15, ty = tid >> 4;
    float b1[8], b2[8]; int x1[8], x2[8];
    #pragma unroll
    for (int i = 0; i < 8; i++){ b1[i] = -INFINITY; b2[i] = -INFINITY; x1[i] = 0; x2[i] = 0; }
    int r4 = (tid & 31) * 4;
    int kr = tid >> 5;
    for (int ct = 0; ct < 8; ct++){
        int m0 = m00 + ct * 128;
        float acc[8][8];
        #pragma unroll
        for (int i = 0; i < 8; i++)
            #pragma unroll
            for (int j = 0; j < 8; j++) acc[i][j] = 0.f;
        for (int kt = 0; kt < 8; kt++){
            int k0 = kt * 32;
            #pragma unroll
            for (int u = 0; u < 4; u++){
                int k = kr + 8 * u;
                *(float4*)&Al[k][r4] = *(const float4*)&Ab[(size_t)(k0 + k) * Lp + l0 + r4];
                *(float4*)&Bl[k][r4] = *(const float4*)&Bb[(size_t)(k0 + k) * Lp + m0 + r4];
            }
            __syncthreads();
            #pragma unroll 8
            for (int k = 0; k < 32; k++){
                float4 a0 = *(float4*)&Al[k][ty*4];
                float4 a1 = *(float4*)&Al[k][64 + ty*4];
                float4 c0 = *(float4*)&Bl[k][tx*4];
                float4 c1 = *(float4*)&Bl[k][64 + tx*4];
                float av[8] = {a0.x,a0.y,a0.z,a0.w,a1.x,a1.y,a1.z,a1.w};
                float bv[8] = {c0.x,c0.y,c0.z,c0.w,c1.x,c1.y,c1.z,c1.w};
                #pragma unroll
                for (int i = 0; i < 8; i++)
                    #pragma unroll
                    for (int j = 0; j < 8; j++)
                        acc[i][j] = fmaf(av[i], bv[j], acc[i][j]);
            }
            __syncthreads();
        }
        // per-thread top-2 update (cols ascending -> first-occurrence ties)
        #pragma unroll
        for (int i = 0; i < 8; i++){
            #pragma unroll
            for (int j = 0; j < 8; j++){
                float v = acc[i][j];
                int col = m0 + ((j < 4) ? tx*4 + j : 64 + tx*4 + (j - 4));
                if (v > b1[i]) { b2[i] = b1[i]; x2[i] = x1[i]; b1[i] = v; x1[i] = col; }
                else if (v > b2[i]) { b2[i] = v; x2[i] = col; }
            }
        }
    }
    // cross-lane top-2 merge over tx group (16 lanes)
    #pragma unroll
    for (int i = 0; i < 8; i++){
        for (int off = 1; off < 16; off <<= 1){
            float q1 = __shfl_xor(b1[i], off, 64); int qi1 = __shfl_xor(x1[i], off, 64);
            float q2 = __shfl_xor(b2[i], off, 64); int qi2 = __shfl_xor(x2[i], off, 64);
            bool qtop = (q1 > b1[i]) || (q1 == b1[i] && qi1 < x1[i]);
            if (qtop){
                float s; int si;
                if (b1[i] > q2 || (b1[i] == q2 && x1[i] < qi2)) { s = b1[i]; si = x1[i]; }
                else { s = q2; si = qi2; }
                b1[i] = q1; x1[i] = qi1; b2[i] = s; x2[i] = si;
            } else {
                float s; int si;
                if (b2[i] > q1 || (b2[i] == q1 && x2[i] < qi1)) { s = b2[i]; si = x2[i]; }
                else { s = q1; si = qi1; }
                b2[i] = s; x2[i] = si;
            }
        }
    }
    if (tx == 0){
        #pragma unroll
        for (int i = 0; i < 8; i++){
            int r = (i < 4) ? ty*4 + i : 64 + ty*4 + (i - 4);
            size_t gid = (size_t)bn * Lp + l0 + r;
            pval[gid*4 + half*2 + 0] = b1[i];
            pval[gid*4 + half*2 + 1] = b2[i];
            pidx[gid*4 + half*2 + 0] = x1[i];
            pidx[gid*4 + half*2 + 1] = x2[i];
        }
    }
}

__global__ void reset_kernel(int* count){ *count = 0; }

__global__ void combine_kernel(const float* __restrict__ pval, const int* __restrict__ pidx,
                               int* __restrict__ bestIdx, int* __restrict__ cand2,
                               float* __restrict__ outF, const int* __restrict__ baseIdx,
                               int* __restrict__ count, int* __restrict__ list)
{
    int gid = blockIdx.x * blockDim.x + threadIdx.x;
    if (gid < Bp*Np*Lp){
        float p1 = pval[gid*4+0], p2 = pval[gid*4+1];
        int  pi1 = pidx[gid*4+0], pi2 = pidx[gid*4+1];
        float q1 = pval[gid*4+2], q2 = pval[gid*4+3];
        int  qi1 = pidx[gid*4+2], qi2 = pidx[gid*4+3];
        float v1, v2; int i1, i2;
        bool qtop = (q1 > p1) || (q1 == p1 && qi1 < pi1);
        if (qtop){
            v1 = q1; i1 = qi1;
            if (p1 > q2 || (p1 == q2 && pi1 < qi2)) { v2 = p1; i2 = pi1; }
            else { v2 = q2; i2 = qi2; }
        } else {
            v1 = p1; i1 = pi1;
            if (p2 > q1 || (p2 == q1 && pi2 < qi1)) { v2 = p2; i2 = pi2; }
            else { v2 = q1; i2 = qi1; }
        }
        bestIdx[gid] = i1; cand2[gid] = i2;
        outF[OUT_REF_OFF + gid] = (float)i1;
        if (v1 - v2 < 1e-4f){
            int s = atomicAdd(count, 1);
            if (s < Bp*Np*Lp) list[s] = gid;
        }
    }
    if (gid < Bp*Lp) outF[OUT_BASE_OFF + gid] = (float)baseIdx[gid];
}

// fp64 re-decision for ambiguous rows
__global__ void refine_kernel(const float* __restrict__ A_T, const float* __restrict__ B_T,
                              const int* __restrict__ count, const int* __restrict__ list,
                              int* __restrict__ bestIdx, const int* __restrict__ cand2,
                              float* __restrict__ outF)
{
    __shared__ double sr[8];
    int n = *count; if (n > Bp*Np*Lp) n = Bp*Np*Lp;
    int tid = threadIdx.x; int lane = tid & 63; int wid = tid >> 6;
    for (int it = blockIdx.x; it < n; it += gridDim.x){
        int gid = list[it];
        int bn = gid >> 11, l = gid & 2047;
        int b = bn / 3;
        int i1 = bestIdx[gid], i2 = cand2[gid];
        const float* ac  = A_T + (size_t)b  * Cp * Lp + l;
        const float* bc1 = B_T + (size_t)bn * Cp * Lp + i1;
        const float* bc2 = B_T + (size_t)bn * Cp * Lp + i2;
        double a  = (double)ac [(size_t)tid * Lp];
        double d1 = a * (double)bc1[(size_t)tid * Lp];
        double d2 = a * (double)bc2[(size_t)tid * Lp];
        #pragma unroll
        for (int off = 32; off; off >>= 1){
            d1 += __shfl_xor(d1, off, 64);
            d2 += __shfl_xor(d2, off, 64);
        }
        if (lane == 0){ sr[wid] = d1; sr[4 + wid] = d2; }
        __syncthreads();
        if (tid == 0){
            double t1 = sr[0] + sr[1] + sr[2] + sr[3];
            double t2 = sr[4] + sr[5] + sr[6] + sr[7];
            int ix = (t2 > t1 || (t2 == t1 && i2 < i1)) ? i2 : i1;
            bestIdx[gid] = ix;
            outF[OUT_REF_OFF + gid] = (float)ix;
        }
        __syncthreads();
    }
}

__global__ void fuse_scatter_kernel(const float* __restrict__ A_T, const float* __restrict__ B_T,
                                    const float* __restrict__ normA, const int* __restrict__ bestIdx,
                                    const int* __restrict__ baseIdx, const float* __restrict__ sim,
                                    const int* __restrict__ pindex, float* __restrict__ out)
{
    int tile = blockIdx.x & 255;          // L/8
    int b = blockIdx.x >> 8;
    int iv = *pindex;
    float bs  = sim[b*4 + iv];
    float rs0 = sim[b*4 + ((0 < iv) ? 0 : 1)];
    float rs1 = sim[b*4 + ((1 < iv) ? 1 : 2)];
    float rs2 = sim[b*4 + ((2 < iv) ? 2 : 3)];
    int c = threadIdx.x;
    const float* Ab = A_T + ((size_t)b * Cp + c) * Lp;
    const float* B0 = B_T + ((size_t)(b*3 + 0) * Cp + c) * Lp;
    const float* B1 = B_T + ((size_t)(b*3 + 1) * Cp + c) * Lp;
    const float* B2 = B_T + ((size_t)(b*3 + 2) * Cp + c) * Lp;
    float* ob = out + ((size_t)b * Cp + c) * HWp;
    for (int j = 0; j < 8; j++){
        int l = tile * 8 + j;
        int pos = baseIdx[b * Lp + l];
        float v = bs * Ab[l] * normA[b * Lp + l];
        v += rs0 * B0[bestIdx[(b*3 + 0) * Lp + l]];
        v += rs1 * B1[bestIdx[(b*3 + 1) * Lp + l]];
        v += rs2 * B2[bestIdx[(b*3 + 2) * Lp + l]];
        ob[pos] = v;
    }
}

extern "C" void kernel_launch(void* const* d_in, const int* in_sizes, int n_in,
                              void* d_out, int out_size, void* d_ws, size_t ws_size,
                              hipStream_t stream)
{
    const float* feat    = (const float*)d_in[0];
    const float* refs    = (const float*)d_in[1];
    const float* sim     = (const float*)d_in[2];
    const int*   baseIdx = (const int*)d_in[3];
    const int*   refIdxI = (const int*)d_in[4];
    const int*   pindex  = (const int*)d_in[5];
    float* out = (float*)d_out;
    float* ws  = (float*)d_ws;

    float* A_T   = ws + WS_AT;
    float* B_T   = ws + WS_BT;
    float* normA = ws + WS_NORMA;
    float* pval  = ws + WS_PVAL;
    int*   pidx  = (int*)(ws + WS_PIDX);
    int*   best  = (int*)(ws + WS_BEST);
    int*   cand2 = (int*)(ws + WS_CAND2);
    int*   count = (int*)(ws + WS_COUNT);
    int*   list  = (int*)(ws + WS_LIST);

    copy_feat_kernel<<<2048, 256, 0, stream>>>((const float4*)feat, (float4*)out, OUT_FEAT_N / 4);
    gather_norm_kernel<<<1024, 256, 0, stream>>>(feat, baseIdx, pindex, A_T, normA, 1, 0);
    gather_norm_kernel<<<3072, 256, 0, stream>>>(refs, refIdxI, pindex, B_T, nullptr, 3, 1);
    gemm_argmax_kernel<<<768, 256, 0, stream>>>(A_T, B_T, pval, pidx);
    reset_kernel<<<1, 1, 0, stream>>>(count);
    combine_kernel<<<192, 256, 0, stream>>>(pval, pidx, best, cand2, out, baseIdx, count, list);
    refine_kernel<<<256, 256, 0, stream>>>(A_T, B_T, count, list, best, cand2, out);
    fuse_scatter_kernel<<<2048, 256, 0, stream>>>(A_T, B_T, normA, best, baseIdx, sim, pindex, out);
}

// Round 2
// 597.950 us; speedup vs baseline: 1.9777x; 1.9777x over previous
//
#include <hip/hip_runtime.h>
#include <math.h>

#define HWp 4096
#define Cp 256
#define Lp 2048
#define Np 3
#define Bp 8

#define OUT_FEAT_N 8388608      // 8*256*4096
#define OUT_BASE_OFF 8388608
#define OUT_REF_OFF 8404992     // + 8*2048
#define NROWS 49152             // 24*2048

// ---- ws byte offsets ----
#define OFF_AT    ((size_t)0)              // A_T fp32 [8][2048][256]   = 16,777,216 B
#define OFF_BT    ((size_t)16777216)       // B_T fp32 [24][2048][256]  = 50,331,648 B
#define OFF_BSPL  ((size_t)67108864)       // B split tiles [24][64][32768] = 50,331,648 B
#define OFF_NORMA ((size_t)117440512)      // 8*2048*4 = 65,536
#define OFF_PVAL  ((size_t)117506048)      // 49152*4*2*4 = 1,572,864
#define OFF_PPX   ((size_t)119078912)      // 49152*4*4   = 786,432
#define OFF_BEST  ((size_t)119865344)      // 196,608
#define OFF_CAND2 ((size_t)120061952)      // 196,608
#define OFF_COUNT ((size_t)120258560)      // 4
#define OFF_LIST  ((size_t)120258564)      // 196,608

typedef __bf16 bf16x8 __attribute__((ext_vector_type(8)));
typedef float f32x16 __attribute__((ext_vector_type(16)));

__device__ __forceinline__ unsigned short bf16r(float x){
    unsigned u = __float_as_uint(x);
    return (unsigned short)((u + 0x7fffu + ((u >> 16) & 1u)) >> 16);
}

__global__ void copy_feat_kernel(const float4* __restrict__ src, float4* __restrict__ dst, int n4){
    int i = blockIdx.x * blockDim.x + threadIdx.x;
    int stride = gridDim.x * blockDim.x;
    for (; i < n4; i += stride) dst[i] = src[i];
}

// Gather selected columns, l2-normalize over c.
// Writes fp32 row-major [group][L][C]; for refs also writes bf16 hi/lo split tiles
// (tile layout: per 32-col tile: [plane 2][ks 16][kh 2][n 32][8 bf16] = 32KB).
__global__ void gather_split_kernel(const float* __restrict__ src,
                                    const int* __restrict__ idx,
                                    const int* __restrict__ pindex,
                                    float* __restrict__ dstF,
                                    unsigned char* __restrict__ dstTiles,
                                    float* __restrict__ normOut,
                                    int nGroups, int isRef)
{
    int tile = blockIdx.x & 63;
    int bg = blockIdx.x >> 6;
    int g = bg % nGroups, b = bg / nGroups;
    const float* sbase;
    if (isRef){
        int iv = *pindex;
        int rn = (g < iv) ? g : g + 1;
        sbase = src + ((size_t)(b*4 + rn)) * Cp * HWp;
    } else {
        sbase = src + ((size_t)b) * Cp * HWp;
    }
    const int* ibase = idx + (size_t)bg * Lp;
    int tid = threadIdx.x, lane = tid & 63, w = tid >> 6;
    for (int j = 0; j < 8; j++){
        int col = tile*32 + w*8 + j;
        int pos = ibase[col];
        const float* cb = sbase + pos;
        float x0 = cb[(size_t)(lane*4+0)*HWp];
        float x1 = cb[(size_t)(lane*4+1)*HWp];
        float x2 = cb[(size_t)(lane*4+2)*HWp];
        float x3 = cb[(size_t)(lane*4+3)*HWp];
        float ss = fmaf(x0,x0, fmaf(x1,x1, fmaf(x2,x2, x3*x3)));
        #pragma unroll
        for (int off = 1; off < 64; off <<= 1) ss += __shfl_xor(ss, off, 64);
        float d = fmaxf(sqrtf(ss), 1e-12f);
        float v0 = x0/d, v1 = x1/d, v2 = x2/d, v3 = x3/d;
        size_t rowbase = ((size_t)bg * Lp + col) * Cp;
        *(float4*)(dstF + rowbase + lane*4) = make_float4(v0, v1, v2, v3);
        if (isRef){
            unsigned short h0 = bf16r(v0), h1 = bf16r(v1), h2 = bf16r(v2), h3 = bf16r(v3);
            float f0 = __uint_as_float((unsigned)h0<<16), f1 = __uint_as_float((unsigned)h1<<16);
            float f2 = __uint_as_float((unsigned)h2<<16), f3 = __uint_as_float((unsigned)h3<<16);
            unsigned short l0 = bf16r(v0-f0), l1 = bf16r(v1-f1), l2 = bf16r(v2-f2), l3 = bf16r(v3-f3);
            unsigned char* tb = dstTiles + ((size_t)bg*64 + tile) * 32768;
            int nn = col & 31;
            int byteoff = (lane>>1)*512 + nn*16 + (lane&1)*8;
            ushort4 hv; hv.x=h0; hv.y=h1; hv.z=h2; hv.w=h3;
            ushort4 lv; lv.x=l0; lv.y=l1; lv.z=l2; lv.w=l3;
            *(ushort4*)(tb + byteoff) = hv;
            *(ushort4*)(tb + 16384 + byteoff) = lv;
        } else {
            if (lane == 0) normOut[(size_t)b*Lp + col] = d;
        }
    }
}

__device__ __forceinline__ void stageB(const unsigned char* g, unsigned char* l){
    #pragma unroll
    for (int p = 0; p < 4; p++)
        __builtin_amdgcn_global_load_lds(
            (const __attribute__((address_space(1))) void*)(g + p*1024),
            (__attribute__((address_space(3))) void*)(l + p*1024),
            16, 0, 0);
}

// bf16x3-split MFMA GEMM with fused per-row top-2 over a 512-col chunk.
// Block: 512 thr (8 waves), 256 rows (32/wave), one (b, rowblk, n, chunk4).
__global__ __launch_bounds__(512, 2) void gemm_mfma_kernel(
    const float* __restrict__ A_T, const unsigned char* __restrict__ Btiles,
    float* __restrict__ pval, unsigned int* __restrict__ ppx)
{
    int bid = blockIdx.x;
    int chunk = bid % 12;          // n = chunk>>2, c4 = chunk&3
    int rowblk = (bid / 12) & 7;
    int b = bid / 96;
    int n = chunk >> 2, c4 = chunk & 3;
    int bn = b*3 + n;
    int tid = threadIdx.x, lane = tid & 63, w = tid >> 6;
    int lh = lane >> 5, l31 = lane & 31;

    __shared__ unsigned char bufs[2][32768];

    // ---- A fragments: load fp32 row, split to bf16 hi/lo in regs ----
    const float* Arow = A_T + ((size_t)b*Lp + rowblk*256 + w*32 + l31) * Cp + lh*8;
    union U8 { unsigned short s[8]; bf16x8 v; };
    U8 AH[16], AL[16];
    #pragma unroll
    for (int ks = 0; ks < 16; ks++){
        float4 fa = *(const float4*)(Arow + ks*16);
        float4 fb = *(const float4*)(Arow + ks*16 + 4);
        float xs[8] = {fa.x, fa.y, fa.z, fa.w, fb.x, fb.y, fb.z, fb.w};
        #pragma unroll
        for (int jj = 0; jj < 8; jj++){
            unsigned short h = bf16r(xs[jj]);
            float hf = __uint_as_float((unsigned)h << 16);
            unsigned short lo = bf16r(xs[jj] - hf);
            AH[ks].s[jj] = h; AL[ks].s[jj] = lo;
        }
    }

    // top-2 state per acc reg (16 rows per lane)
    float tv1[16], tv2[16]; unsigned px[16];
    #pragma unroll
    for (int r = 0; r < 16; r++){ tv1[r] = -INFINITY; tv2[r] = -INFINITY; px[r] = 0; }

    const unsigned char* tbase0 = Btiles + ((size_t)bn*64 + c4*16) * 32768;

    // prologue stage tile 0
    stageB(tbase0 + w*4096 + lane*16, &bufs[0][w*4096]);

    #pragma unroll 1
    for (int t = 0; t < 16; t++){
        if (t < 15){
            stageB(tbase0 + (size_t)(t+1)*32768 + w*4096 + lane*16, &bufs[(t+1)&1][w*4096]);
            asm volatile("s_waitcnt vmcnt(4)" ::: "memory");
        } else {
            asm volatile("s_waitcnt vmcnt(0)" ::: "memory");
        }
        __builtin_amdgcn_s_barrier();

        const unsigned char* bp = bufs[t & 1];
        f32x16 acc;
        #pragma unroll
        for (int r = 0; r < 16; r++) acc[r] = 0.f;
        #pragma unroll
        for (int ks = 0; ks < 16; ks++){
            bf16x8 bh = *(const bf16x8*)(bp + ks*1024 + lh*512 + l31*16);
            bf16x8 bl = *(const bf16x8*)(bp + 16384 + ks*1024 + lh*512 + l31*16);
            acc = __builtin_amdgcn_mfma_f32_32x32x16_bf16(AH[ks].v, bh, acc, 0, 0, 0);
            acc = __builtin_amdgcn_mfma_f32_32x32x16_bf16(AH[ks].v, bl, acc, 0, 0, 0);
            acc = __builtin_amdgcn_mfma_f32_32x32x16_bf16(AL[ks].v, bh, acc, 0, 0, 0);
        }
        __builtin_amdgcn_s_barrier();

        // top-2 update; col identical for all regs
        unsigned col = (unsigned)(t*32 + l31);     // chunk-local 0..511
        #pragma unroll
        for (int r = 0; r < 16; r++){
            float v = acc[r];
            bool c1 = v > tv1[r];
            bool c2 = v > tv2[r];
            unsigned pa = (px[r] << 16) | col;                 // new top: old x1 -> x2
            unsigned pb = (px[r] & 0xffffu) | (col << 16);     // new second
            float nv2 = c1 ? tv1[r] : (c2 ? v : tv2[r]);
            unsigned npx = c1 ? pa : (c2 ? pb : px[r]);
            float nv1 = c1 ? v : tv1[r];
            tv1[r] = nv1; tv2[r] = nv2; px[r] = npx;
        }
    }

    // ---- cross-lane top-2 merge within each 32-lane half ----
    unsigned rowb = (unsigned)(bn*Lp + rowblk*256 + w*32);
    #pragma unroll
    for (int r = 0; r < 16; r++){
        float v1 = tv1[r], v2 = tv2[r];
        int x1 = (int)(px[r] & 0xffffu), x2 = (int)(px[r] >> 16);
        #pragma unroll
        for (int off = 1; off < 32; off <<= 1){
            float q1 = __shfl_xor(v1, off, 64); int qx1 = __shfl_xor(x1, off, 64);
            float q2 = __shfl_xor(v2, off, 64); int qx2 = __shfl_xor(x2, off, 64);
            bool qtop = (q1 > v1) || (q1 == v1 && qx1 < x1);
            if (qtop){
                float s; int si;
                if (v1 > q2 || (v1 == q2 && x1 < qx2)) { s = v1; si = x1; }
                else { s = q2; si = qx2; }
                v1 = q1; x1 = qx1; v2 = s; x2 = si;
            } else {
                if (q1 > v2 || (q1 == v2 && qx1 < x2)) { v2 = q1; x2 = qx1; }
            }
        }
        if (l31 == 0){
            int row_local = (r & 3) + 8*(r >> 2) + 4*lh;
            size_t slot = ((size_t)rowb + row_local) * 4 + c4;
            pval[slot*2 + 0] = v1;
            pval[slot*2 + 1] = v2;
            ppx[slot] = (unsigned)x1 | ((unsigned)x2 << 16);
        }
    }
}

__global__ void reset_kernel(int* count){ *count = 0; }

__global__ void combine_kernel(const float* __restrict__ pval, const unsigned int* __restrict__ ppx,
                               int* __restrict__ best, int* __restrict__ cand2,
                               float* __restrict__ outF, const int* __restrict__ baseIdx,
                               int* __restrict__ count, int* __restrict__ list)
{
    int gid = blockIdx.x * blockDim.x + threadIdx.x;
    if (gid < NROWS){
        float V1 = -INFINITY, V2 = -INFINITY; int X1 = 0, X2 = 0;
        #pragma unroll
        for (int ch = 0; ch < 4; ch++){
            size_t slot = (size_t)gid*4 + ch;
            float a1 = pval[slot*2], a2 = pval[slot*2 + 1];
            unsigned p = ppx[slot];
            int y1 = (int)(p & 0xffffu) + ch*512;
            int y2 = (int)(p >> 16) + ch*512;
            if (a1 > V1 || (a1 == V1 && y1 < X1)){
                if (V1 > a2 || (V1 == a2 && X1 < y2)) { V2 = V1; X2 = X1; }
                else { V2 = a2; X2 = y2; }
                V1 = a1; X1 = y1;
            } else {
                if (a1 > V2 || (a1 == V2 && y1 < X2)) { V2 = a1; X2 = y1; }
            }
        }
        best[gid] = X1; cand2[gid] = X2;
        outF[OUT_REF_OFF + gid] = (float)X1;
        if (V1 - V2 < 1e-4f){
            int s = atomicAdd(count, 1);
            if (s < NROWS) list[s] = gid;
        }
    }
    if (gid < Bp*Lp) outF[OUT_BASE_OFF + gid] = (float)baseIdx[gid];
}

// fp64 re-decision for ambiguous rows (one wave per row)
__global__ void refine_kernel(const float* __restrict__ A_T, const float* __restrict__ B_T,
                              const int* __restrict__ count, const int* __restrict__ list,
                              int* __restrict__ best, const int* __restrict__ cand2,
                              float* __restrict__ outF)
{
    int nf = *count; if (nf > NROWS) nf = NROWS;
    int lane = threadIdx.x;
    for (int it = blockIdx.x; it < nf; it += gridDim.x){
        int gid = list[it];
        int bn = gid >> 11, l = gid & 2047;
        int b = bn / 3;
        int i1 = best[gid], i2 = cand2[gid];
        const float* ar  = A_T + ((size_t)b*Lp + l) * Cp;
        const float* b1r = B_T + ((size_t)bn*Lp + i1) * Cp;
        const float* b2r = B_T + ((size_t)bn*Lp + i2) * Cp;
        double d1 = 0.0, d2 = 0.0;
        #pragma unroll
        for (int i = 0; i < 4; i++){
            double a = (double)ar[lane*4 + i];
            d1 += a * (double)b1r[lane*4 + i];
            d2 += a * (double)b2r[lane*4 + i];
        }
        #pragma unroll
        for (int off = 1; off < 64; off <<= 1){
            d1 += __shfl_xor(d1, off, 64);
            d2 += __shfl_xor(d2, off, 64);
        }
        if (lane == 0){
            int ix = (d2 > d1 || (d2 == d1 && i2 < i1)) ? i2 : i1;
            best[gid] = ix;
            outF[OUT_REF_OFF + gid] = (float)ix;
        }
    }
}

__global__ void fuse_scatter_kernel(const float* __restrict__ A_T, const float* __restrict__ B_T,
                                    const float* __restrict__ normA, const int* __restrict__ best,
                                    const int* __restrict__ baseIdx, const float* __restrict__ sim,
                                    const int* __restrict__ pindex, float* __restrict__ out)
{
    int tile = blockIdx.x & 255;
    int b = blockIdx.x >> 8;
    int iv = *pindex;
    float bs  = sim[b*4 + iv];
    float rs0 = sim[b*4 + ((0 < iv) ? 0 : 1)];
    float rs1 = sim[b*4 + ((1 < iv) ? 1 : 2)];
    float rs2 = sim[b*4 + ((2 < iv) ? 2 : 3)];
    int c = threadIdx.x;
    float* ob = out + ((size_t)b*Cp + c) * HWp;
    for (int j = 0; j < 8; j++){
        int l = tile*8 + j;
        int pos = baseIdx[b*Lp + l];
        float v = bs * A_T[((size_t)b*Lp + l)*Cp + c] * normA[b*Lp + l];
        v += rs0 * B_T[((size_t)(b*3 + 0)*Lp + best[(b*3 + 0)*Lp + l])*Cp + c];
        v += rs1 * B_T[((size_t)(b*3 + 1)*Lp + best[(b*3 + 1)*Lp + l])*Cp + c];
        v += rs2 * B_T[((size_t)(b*3 + 2)*Lp + best[(b*3 + 2)*Lp + l])*Cp + c];
        ob[pos] = v;
    }
}

extern "C" void kernel_launch(void* const* d_in, const int* in_sizes, int n_in,
                              void* d_out, int out_size, void* d_ws, size_t ws_size,
                              hipStream_t stream)
{
    const float* feat    = (const float*)d_in[0];
    const float* refs    = (const float*)d_in[1];
    const float* sim     = (const float*)d_in[2];
    const int*   baseIdx = (const int*)d_in[3];
    const int*   refIdxI = (const int*)d_in[4];
    const int*   pindex  = (const int*)d_in[5];
    float* out = (float*)d_out;
    unsigned char* ws = (unsigned char*)d_ws;

    float* A_T   = (float*)(ws + OFF_AT);
    float* B_T   = (float*)(ws + OFF_BT);
    unsigned char* Btiles = ws + OFF_BSPL;
    float* normA = (float*)(ws + OFF_NORMA);
    float* pval  = (float*)(ws + OFF_PVAL);
    unsigned int* ppx = (unsigned int*)(ws + OFF_PPX);
    int* best  = (int*)(ws + OFF_BEST);
    int* cand2 = (int*)(ws + OFF_CAND2);
    int* count = (int*)(ws + OFF_COUNT);
    int* list  = (int*)(ws + OFF_LIST);

    copy_feat_kernel<<<2048, 256, 0, stream>>>((const float4*)feat, (float4*)out, OUT_FEAT_N/4);
    gather_split_kernel<<<512, 256, 0, stream>>>(feat, baseIdx, pindex, A_T, nullptr, normA, 1, 0);
    gather_split_kernel<<<1536, 256, 0, stream>>>(refs, refIdxI, pindex, B_T, Btiles, nullptr, 3, 1);
    gemm_mfma_kernel<<<768, 512, 0, stream>>>(A_T, Btiles, pval, ppx);
    reset_kernel<<<1, 1, 0, stream>>>(count);
    combine_kernel<<<192, 256, 0, stream>>>(pval, ppx, best, cand2, out, baseIdx, count, list);
    refine_kernel<<<256, 64, 0, stream>>>(A_T, B_T, count, list, best, cand2, out);
    fuse_scatter_kernel<<<2048, 256, 0, stream>>>(A_T, B_T, normA, best, baseIdx, sim, pindex, out);
}

// Round 3
// 329.458 us; speedup vs baseline: 3.5893x; 1.8150x over previous
//
#include <hip/hip_runtime.h>
#include <math.h>

#define HWp 4096
#define Cp 256
#define Lp 2048
#define Np 3
#define Bp 8

#define OUT_FEAT_N 8388608      // 8*256*4096
#define OUT_BASE_OFF 8388608
#define OUT_REF_OFF 8404992     // + 8*2048
#define NROWS 49152             // 24*2048

// ---- ws byte offsets ----
#define OFF_AT    ((size_t)0)              // A_T fp32 [8][2048][256]   = 16,777,216 B
#define OFF_BT    ((size_t)16777216)       // B_T fp32 [24][2048][256]  = 50,331,648 B
#define OFF_BSPL  ((size_t)67108864)       // Btiles [24][64][32768]    = 50,331,648 B
#define OFF_PVAL  ((size_t)117440512)      // 49152*4*2*4 = 1,572,864
#define OFF_PPX   ((size_t)119013376)      // 49152*4*4   = 786,432
#define OFF_BEST  ((size_t)119799808)      // 196,608
#define OFF_CAND2 ((size_t)119996416)      // 196,608
#define OFF_COUNT ((size_t)120193024)      // 4 (pad to 256)
#define OFF_LIST  ((size_t)120193280)      // 196,608
#define OFF_INV   ((size_t)120389888)      // 32*4096*4 = 524,288

typedef __bf16 bf16x8 __attribute__((ext_vector_type(8)));
typedef float f32x16 __attribute__((ext_vector_type(16)));

__device__ __forceinline__ unsigned short bf16r(float x){
    unsigned u = __float_as_uint(x);
    return (unsigned short)((u + 0x7fffu + ((u >> 16) & 1u)) >> 16);
}

__global__ void init_inv_kernel(int4* __restrict__ inv4){
    int tid = blockIdx.x * blockDim.x + threadIdx.x;   // 32768 int4
    if (tid < 32768) inv4[tid] = make_int4(-1, -1, -1, -1);
}

__global__ void scatter_inv_kernel(const int* __restrict__ refIdxI,
                                   const int* __restrict__ baseIdx,
                                   int* __restrict__ inv){
    int tid = blockIdx.x * blockDim.x + threadIdx.x;   // 65536
    if (tid < NROWS){
        int g = tid >> 11;
        inv[g*4096 + refIdxI[tid]] = tid & 2047;
    } else if (tid < NROWS + Bp*Lp){
        int t = tid - NROWS;
        int b = t >> 11;
        inv[(24 + b)*4096 + baseIdx[t]] = t & 2047;
    }
}

// Transpose-gather: per (group, 64-hw tile): coalesced read, LDS transpose
// (xor-swizzled), per-selected-column l2-normalize + write [dest][c] rows.
// groups 0..23 = refs (bn), 24..31 = feat (b).
__global__ __launch_bounds__(256) void gather_kernel(
    const float* __restrict__ feat, const float* __restrict__ refs,
    const int* __restrict__ pindex, const int* __restrict__ inv,
    float* __restrict__ A_T, float* __restrict__ B_T,
    unsigned char* __restrict__ Btiles)
{
    int tileh = blockIdx.x & 63;
    int g = blockIdx.x >> 6;
    int isRef = (g < 24);
    const float* src;
    int b;
    if (isRef){
        b = g / 3; int r0 = g - b*3; int iv = *pindex;
        int rn = (r0 < iv) ? r0 : r0 + 1;
        src = refs + ((size_t)(b*4 + rn)) * Cp * HWp;
    } else {
        b = g - 24;
        src = feat + (size_t)b * Cp * HWp;
    }
    __shared__ float lds[64 * 256];       // [hw][c], xor-swizzled, 64KB
    int tid = threadIdx.x, hwl = tid & 63, cg = tid >> 6;
    int hw0 = tileh * 64;
    const float* sp = src + hw0 + hwl;
    int swz = (hwl & 7) << 3;
    float* lrow = lds + hwl * 256;
    #pragma unroll
    for (int i = 0; i < 16; i++){
        int c0 = cg * 64 + i * 4;
        float x0 = sp[(size_t)(c0 + 0) * HWp];
        float x1 = sp[(size_t)(c0 + 1) * HWp];
        float x2 = sp[(size_t)(c0 + 2) * HWp];
        float x3 = sp[(size_t)(c0 + 3) * HWp];
        *(float4*)(lrow + (c0 ^ swz)) = make_float4(x0, x1, x2, x3);
    }
    __syncthreads();
    int w = cg, lane = tid & 63;
    const int* invg = inv + g * 4096 + hw0;
    for (int h = w * 16; h < w * 16 + 16; h++){
        int dest = invg[h];
        if (dest < 0) continue;
        float4 v = *(float4*)(lds + h * 256 + ((lane * 4) ^ ((h & 7) << 3)));
        float ssq = v.x*v.x + v.y*v.y + v.z*v.z + v.w*v.w;
        #pragma unroll
        for (int off = 1; off < 64; off <<= 1) ssq += __shfl_xor(ssq, off, 64);
        float dn = fmaxf(sqrtf(ssq), 1e-12f);
        v.x /= dn; v.y /= dn; v.z /= dn; v.w /= dn;
        if (isRef){
            size_t row = ((size_t)g * Lp + dest) * Cp;
            *(float4*)(B_T + row + lane * 4) = v;
            unsigned short h0 = bf16r(v.x), h1 = bf16r(v.y), h2 = bf16r(v.z), h3 = bf16r(v.w);
            float f0 = __uint_as_float((unsigned)h0 << 16), f1 = __uint_as_float((unsigned)h1 << 16);
            float f2 = __uint_as_float((unsigned)h2 << 16), f3 = __uint_as_float((unsigned)h3 << 16);
            unsigned short l0 = bf16r(v.x - f0), l1 = bf16r(v.y - f1);
            unsigned short l2 = bf16r(v.z - f2), l3 = bf16r(v.w - f3);
            unsigned char* tb = Btiles + ((size_t)g * 64 + (dest >> 5)) * 32768;
            int nn = dest & 31;
            int byteoff = (lane >> 1) * 512 + nn * 16 + (lane & 1) * 8;
            ushort4 hv; hv.x = h0; hv.y = h1; hv.z = h2; hv.w = h3;
            ushort4 lv; lv.x = l0; lv.y = l1; lv.z = l2; lv.w = l3;
            *(ushort4*)(tb + byteoff) = hv;
            *(ushort4*)(tb + 16384 + byteoff) = lv;
        } else {
            size_t row = ((size_t)b * Lp + dest) * Cp;
            *(float4*)(A_T + row + lane * 4) = v;
        }
    }
}

__device__ __forceinline__ void stageB(const unsigned char* g, unsigned char* l){
    #pragma unroll
    for (int p = 0; p < 4; p++)
        __builtin_amdgcn_global_load_lds(
            (const __attribute__((address_space(1))) void*)(g + p*1024),
            (__attribute__((address_space(3))) void*)(l + p*1024),
            16, 0, 0);
}

// bf16x3-split MFMA GEMM with fused per-row top-2 over a 512-col chunk.
__global__ __launch_bounds__(512, 2) void gemm_mfma_kernel(
    const float* __restrict__ A_T, const unsigned char* __restrict__ Btiles,
    float* __restrict__ pval, unsigned int* __restrict__ ppx)
{
    int bid = blockIdx.x;
    int chunk = bid % 12;
    int rowblk = (bid / 12) & 7;
    int b = bid / 96;
    int n = chunk >> 2, c4 = chunk & 3;
    int bn = b*3 + n;
    int tid = threadIdx.x, lane = tid & 63, w = tid >> 6;
    int lh = lane >> 5, l31 = lane & 31;

    __shared__ unsigned char bufs[2][32768];

    const float* Arow = A_T + ((size_t)b*Lp + rowblk*256 + w*32 + l31) * Cp + lh*8;
    union U8 { unsigned short s[8]; bf16x8 v; };
    U8 AH[16], AL[16];
    #pragma unroll
    for (int ks = 0; ks < 16; ks++){
        float4 fa = *(const float4*)(Arow + ks*16);
        float4 fb = *(const float4*)(Arow + ks*16 + 4);
        float xs[8] = {fa.x, fa.y, fa.z, fa.w, fb.x, fb.y, fb.z, fb.w};
        #pragma unroll
        for (int jj = 0; jj < 8; jj++){
            unsigned short h = bf16r(xs[jj]);
            float hf = __uint_as_float((unsigned)h << 16);
            unsigned short lo = bf16r(xs[jj] - hf);
            AH[ks].s[jj] = h; AL[ks].s[jj] = lo;
        }
    }

    float tv1[16], tv2[16]; unsigned px[16];
    #pragma unroll
    for (int r = 0; r < 16; r++){ tv1[r] = -INFINITY; tv2[r] = -INFINITY; px[r] = 0; }

    const unsigned char* tbase0 = Btiles + ((size_t)bn*64 + c4*16) * 32768;
    stageB(tbase0 + w*4096 + lane*16, &bufs[0][w*4096]);

    #pragma unroll 1
    for (int t = 0; t < 16; t++){
        if (t < 15){
            stageB(tbase0 + (size_t)(t+1)*32768 + w*4096 + lane*16, &bufs[(t+1)&1][w*4096]);
            asm volatile("s_waitcnt vmcnt(4)" ::: "memory");
        } else {
            asm volatile("s_waitcnt vmcnt(0)" ::: "memory");
        }
        __builtin_amdgcn_s_barrier();

        const unsigned char* bp = bufs[t & 1];
        f32x16 acc;
        #pragma unroll
        for (int r = 0; r < 16; r++) acc[r] = 0.f;
        #pragma unroll
        for (int ks = 0; ks < 16; ks++){
            bf16x8 bh = *(const bf16x8*)(bp + ks*1024 + lh*512 + l31*16);
            bf16x8 bl = *(const bf16x8*)(bp + 16384 + ks*1024 + lh*512 + l31*16);
            acc = __builtin_amdgcn_mfma_f32_32x32x16_bf16(AH[ks].v, bh, acc, 0, 0, 0);
            acc = __builtin_amdgcn_mfma_f32_32x32x16_bf16(AH[ks].v, bl, acc, 0, 0, 0);
            acc = __builtin_amdgcn_mfma_f32_32x32x16_bf16(AL[ks].v, bh, acc, 0, 0, 0);
        }
        __builtin_amdgcn_s_barrier();

        unsigned col = (unsigned)(t*32 + l31);
        #pragma unroll
        for (int r = 0; r < 16; r++){
            float v = acc[r];
            bool c1 = v > tv1[r];
            bool c2 = v > tv2[r];
            unsigned pa = (px[r] << 16) | col;
            unsigned pb = (px[r] & 0xffffu) | (col << 16);
            float nv2 = c1 ? tv1[r] : (c2 ? v : tv2[r]);
            unsigned npx = c1 ? pa : (c2 ? pb : px[r]);
            float nv1 = c1 ? v : tv1[r];
            tv1[r] = nv1; tv2[r] = nv2; px[r] = npx;
        }
    }

    unsigned rowb = (unsigned)(bn*Lp + rowblk*256 + w*32);
    #pragma unroll
    for (int r = 0; r < 16; r++){
        float v1 = tv1[r], v2 = tv2[r];
        int x1 = (int)(px[r] & 0xffffu), x2 = (int)(px[r] >> 16);
        #pragma unroll
        for (int off = 1; off < 32; off <<= 1){
            float q1 = __shfl_xor(v1, off, 64); int qx1 = __shfl_xor(x1, off, 64);
            float q2 = __shfl_xor(v2, off, 64); int qx2 = __shfl_xor(x2, off, 64);
            bool qtop = (q1 > v1) || (q1 == v1 && qx1 < x1);
            if (qtop){
                float s; int si;
                if (v1 > q2 || (v1 == q2 && x1 < qx2)) { s = v1; si = x1; }
                else { s = q2; si = qx2; }
                v1 = q1; x1 = qx1; v2 = s; x2 = si;
            } else {
                if (q1 > v2 || (q1 == v2 && qx1 < x2)) { v2 = q1; x2 = qx1; }
            }
        }
        if (l31 == 0){
            int row_local = (r & 3) + 8*(r >> 2) + 4*lh;
            size_t slot = ((size_t)rowb + row_local) * 4 + c4;
            pval[slot*2 + 0] = v1;
            pval[slot*2 + 1] = v2;
            ppx[slot] = (unsigned)x1 | ((unsigned)x2 << 16);
        }
    }
}

__global__ void reset_kernel(int* count){ *count = 0; }

__global__ void combine_kernel(const float* __restrict__ pval, const unsigned int* __restrict__ ppx,
                               int* __restrict__ best, int* __restrict__ cand2,
                               float* __restrict__ outF, const int* __restrict__ baseIdx,
                               int* __restrict__ count, int* __restrict__ list)
{
    int gid = blockIdx.x * blockDim.x + threadIdx.x;
    if (gid < NROWS){
        float V1 = -INFINITY, V2 = -INFINITY; int X1 = 0, X2 = 0;
        #pragma unroll
        for (int ch = 0; ch < 4; ch++){
            size_t slot = (size_t)gid*4 + ch;
            float a1 = pval[slot*2], a2 = pval[slot*2 + 1];
            unsigned p = ppx[slot];
            int y1 = (int)(p & 0xffffu) + ch*512;
            int y2 = (int)(p >> 16) + ch*512;
            if (a1 > V1 || (a1 == V1 && y1 < X1)){
                if (V1 > a2 || (V1 == a2 && X1 < y2)) { V2 = V1; X2 = X1; }
                else { V2 = a2; X2 = y2; }
                V1 = a1; X1 = y1;
            } else {
                if (a1 > V2 || (a1 == V2 && y1 < X2)) { V2 = a1; X2 = y1; }
            }
        }
        best[gid] = X1; cand2[gid] = X2;
        outF[OUT_REF_OFF + gid] = (float)X1;
        if (V1 - V2 < 1e-4f){
            int s = atomicAdd(count, 1);
            if (s < NROWS) list[s] = gid;
        }
    }
    if (gid < Bp*Lp) outF[OUT_BASE_OFF + gid] = (float)baseIdx[gid];
}

// fp64 re-decision for ambiguous rows, from RAW inputs (one wave per row).
__global__ void refine_kernel(const float* __restrict__ feat, const float* __restrict__ refs,
                              const int* __restrict__ baseIdx, const int* __restrict__ refIdxI,
                              const int* __restrict__ pindex,
                              const int* __restrict__ count, const int* __restrict__ list,
                              int* __restrict__ best, const int* __restrict__ cand2,
                              float* __restrict__ outF)
{
    int nf = *count; if (nf > NROWS) nf = NROWS;
    int lane = threadIdx.x & 63;
    int iv = *pindex;
    for (int it = blockIdx.x; it < nf; it += gridDim.x){
        int gid = list[it];
        int bn = gid >> 11, l = gid & 2047;
        int b = bn / 3; int r0 = bn - b*3;
        int rn = (r0 < iv) ? r0 : r0 + 1;
        int i1 = best[gid], i2 = cand2[gid];
        int posA = baseIdx[b*Lp + l];
        int pos1 = refIdxI[bn*Lp + i1];
        int pos2 = refIdxI[bn*Lp + i2];
        const float* fA = feat + (size_t)b * Cp * HWp + posA;
        const float* fR = refs + (size_t)(b*4 + rn) * Cp * HWp;
        const float* f1 = fR + pos1;
        const float* f2 = fR + pos2;
        double s1 = 0, s2 = 0, d1 = 0, d2 = 0;
        #pragma unroll
        for (int j = 0; j < 4; j++){
            int c = lane * 4 + j;
            double a  = (double)fA[(size_t)c * HWp];
            double x1 = (double)f1[(size_t)c * HWp];
            double x2 = (double)f2[(size_t)c * HWp];
            s1 += x1*x1; s2 += x2*x2;
            d1 += a*x1;  d2 += a*x2;
        }
        #pragma unroll
        for (int off = 1; off < 64; off <<= 1){
            s1 += __shfl_xor(s1, off, 64);
            s2 += __shfl_xor(s2, off, 64);
            d1 += __shfl_xor(d1, off, 64);
            d2 += __shfl_xor(d2, off, 64);
        }
        if (lane == 0){
            double q1 = d1 * sqrt(s2), q2 = d2 * sqrt(s1);
            int ix = (q2 > q1 || (q2 == q1 && i2 < i1)) ? i2 : i1;
            best[gid] = ix;
            outF[OUT_REF_OFF + gid] = (float)ix;
        }
    }
}

// Tile-based fuse: load feat tile -> LDS (rotation layout, conflict-free),
// overwrite selected columns with fused values, write full tile coalesced.
// Replaces copy_feat + fuse_scatter.
__global__ __launch_bounds__(256) void fuse_tile_kernel(
    const float* __restrict__ feat, const float* __restrict__ B_T,
    const int* __restrict__ best, const int* __restrict__ inv,
    const float* __restrict__ sim, const int* __restrict__ pindex,
    float* __restrict__ out)
{
    int tileh = blockIdx.x & 63;
    int b = blockIdx.x >> 6;
    int hw0 = tileh * 64;
    __shared__ float lds[256 * 64];       // addr(c,hw) = c*64 + ((hw + c) & 63)
    int tid = threadIdx.x, hwl = tid & 63, cg = tid >> 6;
    const float* fb = feat + (size_t)b * Cp * HWp + hw0 + hwl;
    #pragma unroll 4
    for (int i = 0; i < 64; i++){
        int c = cg * 64 + i;
        lds[c * 64 + ((hwl + c) & 63)] = fb[(size_t)c * HWp];
    }
    __syncthreads();
    int iv = *pindex;
    float bs  = sim[b*4 + iv];
    float rs0 = sim[b*4 + ((0 < iv) ? 0 : 1)];
    float rs1 = sim[b*4 + ((1 < iv) ? 1 : 2)];
    float rs2 = sim[b*4 + ((2 < iv) ? 2 : 3)];
    int w = cg, lane = tid & 63;
    const int* invg = inv + (24 + b) * 4096 + hw0;
    for (int h = w * 16; h < w * 16 + 16; h++){
        int dest = invg[h];
        if (dest < 0) continue;
        int b0 = best[(b*3 + 0)*Lp + dest];
        int b1 = best[(b*3 + 1)*Lp + dest];
        int b2 = best[(b*3 + 2)*Lp + dest];
        const float* r0 = B_T + ((size_t)(b*3 + 0)*Lp + b0) * Cp;
        const float* r1 = B_T + ((size_t)(b*3 + 1)*Lp + b1) * Cp;
        const float* r2 = B_T + ((size_t)(b*3 + 2)*Lp + b2) * Cp;
        #pragma unroll
        for (int j = 0; j < 4; j++){
            int c = lane + j * 64;
            int la = c * 64 + ((h + c) & 63);
            float base = lds[la];
            lds[la] = bs*base + rs0*r0[c] + rs1*r1[c] + rs2*r2[c];
        }
    }
    __syncthreads();
    float* ob = out + (size_t)b * Cp * HWp + hw0 + hwl;
    #pragma unroll 4
    for (int i = 0; i < 64; i++){
        int c = cg * 64 + i;
        ob[(size_t)c * HWp] = lds[c * 64 + ((hwl + c) & 63)];
    }
}

extern "C" void kernel_launch(void* const* d_in, const int* in_sizes, int n_in,
                              void* d_out, int out_size, void* d_ws, size_t ws_size,
                              hipStream_t stream)
{
    const float* feat    = (const float*)d_in[0];
    const float* refs    = (const float*)d_in[1];
    const float* sim     = (const float*)d_in[2];
    const int*   baseIdx = (const int*)d_in[3];
    const int*   refIdxI = (const int*)d_in[4];
    const int*   pindex  = (const int*)d_in[5];
    float* out = (float*)d_out;
    unsigned char* ws = (unsigned char*)d_ws;

    float* A_T   = (float*)(ws + OFF_AT);
    float* B_T   = (float*)(ws + OFF_BT);
    unsigned char* Btiles = ws + OFF_BSPL;
    float* pval  = (float*)(ws + OFF_PVAL);
    unsigned int* ppx = (unsigned int*)(ws + OFF_PPX);
    int* best  = (int*)(ws + OFF_BEST);
    int* cand2 = (int*)(ws + OFF_CAND2);
    int* count = (int*)(ws + OFF_COUNT);
    int* list  = (int*)(ws + OFF_LIST);
    int* inv   = (int*)(ws + OFF_INV);

    init_inv_kernel<<<128, 256, 0, stream>>>((int4*)inv);
    scatter_inv_kernel<<<256, 256, 0, stream>>>(refIdxI, baseIdx, inv);
    gather_kernel<<<2048, 256, 0, stream>>>(feat, refs, pindex, inv, A_T, B_T, Btiles);
    gemm_mfma_kernel<<<768, 512, 0, stream>>>(A_T, Btiles, pval, ppx);
    reset_kernel<<<1, 1, 0, stream>>>(count);
    combine_kernel<<<192, 256, 0, stream>>>(pval, ppx, best, cand2, out, baseIdx, count, list);
    refine_kernel<<<256, 64, 0, stream>>>(feat, refs, baseIdx, refIdxI, pindex, count, list, best, cand2, out);
    fuse_tile_kernel<<<512, 256, 0, stream>>>(feat, B_T, best, inv, sim, pindex, out);
}

// Round 4
// 269.960 us; speedup vs baseline: 4.3804x; 1.2204x over previous
//
#include <hip/hip_runtime.h>
#include <math.h>

#define HWp 4096
#define Cp 256
#define Lp 2048
#define Np 3
#define Bp 8

#define OUT_FEAT_N 8388608      // 8*256*4096
#define OUT_BASE_OFF 8388608
#define OUT_REF_OFF 8404992     // + 8*2048
#define NROWS 49152             // 24*2048

// ---- ws byte offsets ----
#define OFF_AT    ((size_t)0)              // A_T fp32 [8][2048][256]   = 16,777,216 B
#define OFF_BT    ((size_t)16777216)       // B_T fp32 [24][2048][256]  = 50,331,648 B
#define OFF_BSPL  ((size_t)67108864)       // Btiles [24][64][16384]    = 25,165,824 B
#define OFF_PVAL  ((size_t)117440512)      // 49152*4*2*4 = 1,572,864
#define OFF_PPX   ((size_t)119013376)      // 49152*4*4   = 786,432
#define OFF_BEST  ((size_t)119799808)      // 196,608
#define OFF_CAND2 ((size_t)119996416)      // 196,608
#define OFF_COUNT ((size_t)120193024)      // 4 (pad to 256)
#define OFF_LIST  ((size_t)120193280)      // 196,608
#define OFF_INV   ((size_t)120389888)      // 32*4096*4 = 524,288

typedef _Float16 f16x8 __attribute__((ext_vector_type(8)));
typedef float f32x16 __attribute__((ext_vector_type(16)));

__device__ __forceinline__ unsigned short f16bits(float x){
    union { _Float16 h; unsigned short s; } u;
    u.h = (_Float16)x;
    return u.s;
}

__global__ void init_inv_kernel(int4* __restrict__ inv4){
    int tid = blockIdx.x * blockDim.x + threadIdx.x;   // 32768 int4
    if (tid < 32768) inv4[tid] = make_int4(-1, -1, -1, -1);
}

__global__ void scatter_inv_kernel(const int* __restrict__ refIdxI,
                                   const int* __restrict__ baseIdx,
                                   int* __restrict__ inv){
    int tid = blockIdx.x * blockDim.x + threadIdx.x;   // 65536
    if (tid < NROWS){
        int g = tid >> 11;
        inv[g*4096 + refIdxI[tid]] = tid & 2047;
    } else if (tid < NROWS + Bp*Lp){
        int t = tid - NROWS;
        int b = t >> 11;
        inv[(24 + b)*4096 + baseIdx[t]] = t & 2047;
    }
}

// Transpose-gather: per (group, 64-hw tile): coalesced read, LDS transpose
// (xor-swizzled), per-selected-column l2-normalize + write [dest][c] rows.
// groups 0..23 = refs (bn), 24..31 = feat (b). Refs also write f16 tiles.
__global__ __launch_bounds__(256) void gather_kernel(
    const float* __restrict__ feat, const float* __restrict__ refs,
    const int* __restrict__ pindex, const int* __restrict__ inv,
    float* __restrict__ A_T, float* __restrict__ B_T,
    unsigned char* __restrict__ Btiles)
{
    int tileh = blockIdx.x & 63;
    int g = blockIdx.x >> 6;
    int isRef = (g < 24);
    const float* src;
    int b;
    if (isRef){
        b = g / 3; int r0 = g - b*3; int iv = *pindex;
        int rn = (r0 < iv) ? r0 : r0 + 1;
        src = refs + ((size_t)(b*4 + rn)) * Cp * HWp;
    } else {
        b = g - 24;
        src = feat + (size_t)b * Cp * HWp;
    }
    __shared__ float lds[64 * 256];       // [hw][c], xor-swizzled, 64KB
    int tid = threadIdx.x, hwl = tid & 63, cg = tid >> 6;
    int hw0 = tileh * 64;
    const float* sp = src + hw0 + hwl;
    int swz = (hwl & 7) << 3;
    float* lrow = lds + hwl * 256;
    #pragma unroll
    for (int i = 0; i < 16; i++){
        int c0 = cg * 64 + i * 4;
        float x0 = sp[(size_t)(c0 + 0) * HWp];
        float x1 = sp[(size_t)(c0 + 1) * HWp];
        float x2 = sp[(size_t)(c0 + 2) * HWp];
        float x3 = sp[(size_t)(c0 + 3) * HWp];
        *(float4*)(lrow + (c0 ^ swz)) = make_float4(x0, x1, x2, x3);
    }
    __syncthreads();
    int w = cg, lane = tid & 63;
    const int* invg = inv + g * 4096 + hw0;
    for (int h = w * 16; h < w * 16 + 16; h++){
        int dest = invg[h];
        if (dest < 0) continue;
        float4 v = *(float4*)(lds + h * 256 + ((lane * 4) ^ ((h & 7) << 3)));
        float ssq = v.x*v.x + v.y*v.y + v.z*v.z + v.w*v.w;
        #pragma unroll
        for (int off = 1; off < 64; off <<= 1) ssq += __shfl_xor(ssq, off, 64);
        float dn = fmaxf(sqrtf(ssq), 1e-12f);
        v.x /= dn; v.y /= dn; v.z /= dn; v.w /= dn;
        if (isRef){
            size_t row = ((size_t)g * Lp + dest) * Cp;
            *(float4*)(B_T + row + lane * 4) = v;
            // f16 single-plane tile: [ks 16][kh 2][n 32][j 8] halves, 16KB/tile
            unsigned char* tb = Btiles + ((size_t)g * 64 + (dest >> 5)) * 16384;
            int nn = dest & 31;
            int byteoff = (lane >> 2) * 1024 + ((lane >> 1) & 1) * 512 + nn * 16 + (lane & 1) * 8;
            ushort4 hv;
            hv.x = f16bits(v.x); hv.y = f16bits(v.y);
            hv.z = f16bits(v.z); hv.w = f16bits(v.w);
            *(ushort4*)(tb + byteoff) = hv;
        } else {
            size_t row = ((size_t)b * Lp + dest) * Cp;
            *(float4*)(A_T + row + lane * 4) = v;
        }
    }
}

__device__ __forceinline__ void stageB(const unsigned char* g, unsigned char* l){
    #pragma unroll
    for (int p = 0; p < 2; p++)
        __builtin_amdgcn_global_load_lds(
            (const __attribute__((address_space(1))) void*)(g + p*1024),
            (__attribute__((address_space(3))) void*)(l + p*1024),
            16, 0, 0);
}

// fp16 A-2-plane (regs) x B-1-plane (LDS) MFMA GEMM, fused per-row top-2
// over a 512-col chunk. Block: 512 thr (8 waves), 256 rows, 16 col-tiles.
__global__ __launch_bounds__(512, 2) void gemm_mfma_kernel(
    const float* __restrict__ A_T, const unsigned char* __restrict__ Btiles,
    float* __restrict__ pval, unsigned int* __restrict__ ppx)
{
    int bid = blockIdx.x;
    int chunk = bid % 12;
    int rowblk = (bid / 12) & 7;
    int b = bid / 96;
    int n = chunk >> 2, c4 = chunk & 3;
    int bn = b*3 + n;
    int tid = threadIdx.x, lane = tid & 63, w = tid >> 6;
    int lh = lane >> 5, l31 = lane & 31;

    __shared__ unsigned char bufs[2][16384];

    // A fragments: fp32 row -> fp16 hi/lo planes in regs
    const float* Arow = A_T + ((size_t)b*Lp + rowblk*256 + w*32 + l31) * Cp + lh*8;
    union U8 { _Float16 h[8]; f16x8 v; };
    U8 AH[16], AL[16];
    #pragma unroll
    for (int ks = 0; ks < 16; ks++){
        float4 fa = *(const float4*)(Arow + ks*16);
        float4 fb = *(const float4*)(Arow + ks*16 + 4);
        float xs[8] = {fa.x, fa.y, fa.z, fa.w, fb.x, fb.y, fb.z, fb.w};
        #pragma unroll
        for (int jj = 0; jj < 8; jj++){
            _Float16 h = (_Float16)xs[jj];
            float hf = (float)h;
            AH[ks].h[jj] = h;
            AL[ks].h[jj] = (_Float16)(xs[jj] - hf);
        }
    }

    float tv1[16], tv2[16]; unsigned px[16];
    #pragma unroll
    for (int r = 0; r < 16; r++){ tv1[r] = -INFINITY; tv2[r] = -INFINITY; px[r] = 0; }

    const unsigned char* tbase0 = Btiles + ((size_t)bn*64 + c4*16) * 16384;
    stageB(tbase0 + w*2048 + lane*16, &bufs[0][w*2048]);

    #pragma unroll 1
    for (int t = 0; t < 16; t++){
        if (t < 15){
            stageB(tbase0 + (size_t)(t+1)*16384 + w*2048 + lane*16, &bufs[(t+1)&1][w*2048]);
            asm volatile("s_waitcnt vmcnt(2)" ::: "memory");
        } else {
            asm volatile("s_waitcnt vmcnt(0)" ::: "memory");
        }
        __builtin_amdgcn_s_barrier();

        const unsigned char* bp = bufs[t & 1];
        f32x16 acc;
        #pragma unroll
        for (int r = 0; r < 16; r++) acc[r] = 0.f;
        #pragma unroll
        for (int ks = 0; ks < 16; ks++){
            f16x8 bh = *(const f16x8*)(bp + ks*1024 + lh*512 + l31*16);
            acc = __builtin_amdgcn_mfma_f32_32x32x16_f16(AH[ks].v, bh, acc, 0, 0, 0);
            acc = __builtin_amdgcn_mfma_f32_32x32x16_f16(AL[ks].v, bh, acc, 0, 0, 0);
        }
        __builtin_amdgcn_s_barrier();

        unsigned col = (unsigned)(t*32 + l31);
        #pragma unroll
        for (int r = 0; r < 16; r++){
            float v = acc[r];
            bool c1 = v > tv1[r];
            bool c2 = v > tv2[r];
            unsigned pa = (px[r] << 16) | col;
            unsigned pb = (px[r] & 0xffffu) | (col << 16);
            float nv2 = c1 ? tv1[r] : (c2 ? v : tv2[r]);
            unsigned npx = c1 ? pa : (c2 ? pb : px[r]);
            float nv1 = c1 ? v : tv1[r];
            tv1[r] = nv1; tv2[r] = nv2; px[r] = npx;
        }
    }

    unsigned rowb = (unsigned)(bn*Lp + rowblk*256 + w*32);
    #pragma unroll
    for (int r = 0; r < 16; r++){
        float v1 = tv1[r], v2 = tv2[r];
        int x1 = (int)(px[r] & 0xffffu), x2 = (int)(px[r] >> 16);
        #pragma unroll
        for (int off = 1; off < 32; off <<= 1){
            float q1 = __shfl_xor(v1, off, 64); int qx1 = __shfl_xor(x1, off, 64);
            float q2 = __shfl_xor(v2, off, 64); int qx2 = __shfl_xor(x2, off, 64);
            bool qtop = (q1 > v1) || (q1 == v1 && qx1 < x1);
            if (qtop){
                float s; int si;
                if (v1 > q2 || (v1 == q2 && x1 < qx2)) { s = v1; si = x1; }
                else { s = q2; si = qx2; }
                v1 = q1; x1 = qx1; v2 = s; x2 = si;
            } else {
                if (q1 > v2 || (q1 == v2 && qx1 < x2)) { v2 = q1; x2 = qx1; }
            }
        }
        if (l31 == 0){
            int row_local = (r & 3) + 8*(r >> 2) + 4*lh;
            size_t slot = ((size_t)rowb + row_local) * 4 + c4;
            pval[slot*2 + 0] = v1;
            pval[slot*2 + 1] = v2;
            ppx[slot] = (unsigned)x1 | ((unsigned)x2 << 16);
        }
    }
}

__global__ void reset_kernel(int* count){ *count = 0; }

__global__ void combine_kernel(const float* __restrict__ pval, const unsigned int* __restrict__ ppx,
                               int* __restrict__ best, int* __restrict__ cand2,
                               float* __restrict__ outF, const int* __restrict__ baseIdx,
                               int* __restrict__ count, int* __restrict__ list)
{
    int gid = blockIdx.x * blockDim.x + threadIdx.x;
    if (gid < NROWS){
        float V1 = -INFINITY, V2 = -INFINITY; int X1 = 0, X2 = 0;
        #pragma unroll
        for (int ch = 0; ch < 4; ch++){
            size_t slot = (size_t)gid*4 + ch;
            float a1 = pval[slot*2], a2 = pval[slot*2 + 1];
            unsigned p = ppx[slot];
            int y1 = (int)(p & 0xffffu) + ch*512;
            int y2 = (int)(p >> 16) + ch*512;
            if (a1 > V1 || (a1 == V1 && y1 < X1)){
                if (V1 > a2 || (V1 == a2 && X1 < y2)) { V2 = V1; X2 = X1; }
                else { V2 = a2; X2 = y2; }
                V1 = a1; X1 = y1;
            } else {
                if (a1 > V2 || (a1 == V2 && y1 < X2)) { V2 = a1; X2 = y1; }
            }
        }
        best[gid] = X1; cand2[gid] = X2;
        outF[OUT_REF_OFF + gid] = (float)X1;
        if (V1 - V2 < 2e-4f){
            int s = atomicAdd(count, 1);
            if (s < NROWS) list[s] = gid;
        }
    }
    if (gid < Bp*Lp) outF[OUT_BASE_OFF + gid] = (float)baseIdx[gid];
}

// fp64 re-decision for ambiguous rows from stored normalized fp32 (coalesced).
__global__ void refine_kernel(const float* __restrict__ A_T, const float* __restrict__ B_T,
                              const int* __restrict__ count, const int* __restrict__ list,
                              int* __restrict__ best, const int* __restrict__ cand2,
                              float* __restrict__ outF)
{
    int nf = *count; if (nf > NROWS) nf = NROWS;
    int lane = threadIdx.x & 63;
    for (int it = blockIdx.x; it < nf; it += gridDim.x){
        int gid = list[it];
        int bn = gid >> 11, l = gid & 2047;
        int b = bn / 3;
        int i1 = best[gid], i2 = cand2[gid];
        const float* ar  = A_T + ((size_t)b*Lp + l) * Cp;
        const float* b1r = B_T + ((size_t)bn*Lp + i1) * Cp;
        const float* b2r = B_T + ((size_t)bn*Lp + i2) * Cp;
        double d1 = 0.0, d2 = 0.0;
        #pragma unroll
        for (int j = 0; j < 4; j++){
            double a = (double)ar[lane*4 + j];
            d1 += a * (double)b1r[lane*4 + j];
            d2 += a * (double)b2r[lane*4 + j];
        }
        #pragma unroll
        for (int off = 1; off < 64; off <<= 1){
            d1 += __shfl_xor(d1, off, 64);
            d2 += __shfl_xor(d2, off, 64);
        }
        if (lane == 0){
            int ix = (d2 > d1 || (d2 == d1 && i2 < i1)) ? i2 : i1;
            best[gid] = ix;
            outF[OUT_REF_OFF + gid] = (float)ix;
        }
    }
}

// Tile-based fuse: load feat tile -> LDS (rotation layout, conflict-free),
// overwrite selected columns with fused values, write full tile coalesced.
__global__ __launch_bounds__(256) void fuse_tile_kernel(
    const float* __restrict__ feat, const float* __restrict__ B_T,
    const int* __restrict__ best, const int* __restrict__ inv,
    const float* __restrict__ sim, const int* __restrict__ pindex,
    float* __restrict__ out)
{
    int tileh = blockIdx.x & 63;
    int b = blockIdx.x >> 6;
    int hw0 = tileh * 64;
    __shared__ float lds[256 * 64];       // addr(c,hw) = c*64 + ((hw + c) & 63)
    int tid = threadIdx.x, hwl = tid & 63, cg = tid >> 6;
    const float* fb = feat + (size_t)b * Cp * HWp + hw0 + hwl;
    #pragma unroll 4
    for (int i = 0; i < 64; i++){
        int c = cg * 64 + i;
        lds[c * 64 + ((hwl + c) & 63)] = fb[(size_t)c * HWp];
    }
    __syncthreads();
    int iv = *pindex;
    float bs  = sim[b*4 + iv];
    float rs0 = sim[b*4 + ((0 < iv) ? 0 : 1)];
    float rs1 = sim[b*4 + ((1 < iv) ? 1 : 2)];
    float rs2 = sim[b*4 + ((2 < iv) ? 2 : 3)];
    int w = cg, lane = tid & 63;
    const int* invg = inv + (24 + b) * 4096 + hw0;
    for (int h = w * 16; h < w * 16 + 16; h++){
        int dest = invg[h];
        if (dest < 0) continue;
        int b0 = best[(b*3 + 0)*Lp + dest];
        int b1 = best[(b*3 + 1)*Lp + dest];
        int b2 = best[(b*3 + 2)*Lp + dest];
        const float* r0 = B_T + ((size_t)(b*3 + 0)*Lp + b0) * Cp;
        const float* r1 = B_T + ((size_t)(b*3 + 1)*Lp + b1) * Cp;
        const float* r2 = B_T + ((size_t)(b*3 + 2)*Lp + b2) * Cp;
        #pragma unroll
        for (int j = 0; j < 4; j++){
            int c = lane + j * 64;
            int la = c * 64 + ((h + c) & 63);
            float base = lds[la];
            lds[la] = bs*base + rs0*r0[c] + rs1*r1[c] + rs2*r2[c];
        }
    }
    __syncthreads();
    float* ob = out + (size_t)b * Cp * HWp + hw0 + hwl;
    #pragma unroll 4
    for (int i = 0; i < 64; i++){
        int c = cg * 64 + i;
        ob[(size_t)c * HWp] = lds[c * 64 + ((hwl + c) & 63)];
    }
}

extern "C" void kernel_launch(void* const* d_in, const int* in_sizes, int n_in,
                              void* d_out, int out_size, void* d_ws, size_t ws_size,
                              hipStream_t stream)
{
    const float* feat    = (const float*)d_in[0];
    const float* refs    = (const float*)d_in[1];
    const float* sim     = (const float*)d_in[2];
    const int*   baseIdx = (const int*)d_in[3];
    const int*   refIdxI = (const int*)d_in[4];
    const int*   pindex  = (const int*)d_in[5];
    float* out = (float*)d_out;
    unsigned char* ws = (unsigned char*)d_ws;

    float* A_T   = (float*)(ws + OFF_AT);
    float* B_T   = (float*)(ws + OFF_BT);
    unsigned char* Btiles = ws + OFF_BSPL;
    float* pval  = (float*)(ws + OFF_PVAL);
    unsigned int* ppx = (unsigned int*)(ws + OFF_PPX);
    int* best  = (int*)(ws + OFF_BEST);
    int* cand2 = (int*)(ws + OFF_CAND2);
    int* count = (int*)(ws + OFF_COUNT);
    int* list  = (int*)(ws + OFF_LIST);
    int* inv   = (int*)(ws + OFF_INV);

    init_inv_kernel<<<128, 256, 0, stream>>>((int4*)inv);
    scatter_inv_kernel<<<256, 256, 0, stream>>>(refIdxI, baseIdx, inv);
    gather_kernel<<<2048, 256, 0, stream>>>(feat, refs, pindex, inv, A_T, B_T, Btiles);
    gemm_mfma_kernel<<<768, 512, 0, stream>>>(A_T, Btiles, pval, ppx);
    reset_kernel<<<1, 1, 0, stream>>>(count);
    combine_kernel<<<192, 256, 0, stream>>>(pval, ppx, best, cand2, out, baseIdx, count, list);
    refine_kernel<<<512, 64, 0, stream>>>(A_T, B_T, count, list, best, cand2, out);
    fuse_tile_kernel<<<512, 256, 0, stream>>>(feat, B_T, best, inv, sim, pindex, out);
}

// Round 5
// 210.807 us; speedup vs baseline: 5.6096x; 1.2806x over previous
//
#include <hip/hip_runtime.h>
#include <math.h>

#define HWp 4096
#define Cp 256
#define Lp 2048
#define Np 3
#define Bp 8

#define OUT_FEAT_N 8388608      // 8*256*4096
#define OUT_BASE_OFF 8388608
#define OUT_REF_OFF 8404992     // + 8*2048
#define NROWS 49152             // 24*2048

// ---- ws byte offsets ----
#define OFF_AT    ((size_t)0)              // A_T fp32 [8][2048][256]   = 16,777,216 B
#define OFF_BT    ((size_t)16777216)       // B_T fp32 [24][2048][256]  = 50,331,648 B
#define OFF_BSPL  ((size_t)67108864)       // Btiles [24][64][16384]    = 25,165,824 B
#define OFF_PVAL  ((size_t)117440512)      // ppk: 49152*4*2*4 = 1,572,864
#define OFF_BEST  ((size_t)119799808)      // 196,608
#define OFF_CAND2 ((size_t)119996416)      // 196,608
#define OFF_COUNT ((size_t)120193024)      // 4 (pad to 256)
#define OFF_LIST  ((size_t)120193280)      // 196,608
#define OFF_INV   ((size_t)120389888)      // 32*4096*4 = 524,288

typedef _Float16 f16x8 __attribute__((ext_vector_type(8)));
typedef float f32x4 __attribute__((ext_vector_type(4)));

__device__ __forceinline__ unsigned short f16bits(float x){
    union { _Float16 h; unsigned short s; } u;
    u.h = (_Float16)x;
    return u.s;
}

__global__ void init_inv_kernel(int4* __restrict__ inv4){
    int tid = blockIdx.x * blockDim.x + threadIdx.x;   // 32768 int4
    if (tid < 32768) inv4[tid] = make_int4(-1, -1, -1, -1);
}

__global__ void scatter_inv_kernel(const int* __restrict__ refIdxI,
                                   const int* __restrict__ baseIdx,
                                   int* __restrict__ inv){
    int tid = blockIdx.x * blockDim.x + threadIdx.x;   // 65536
    if (tid < NROWS){
        int g = tid >> 11;
        inv[g*4096 + refIdxI[tid]] = tid & 2047;
    } else if (tid < NROWS + Bp*Lp){
        int t = tid - NROWS;
        int b = t >> 11;
        inv[(24 + b)*4096 + baseIdx[t]] = t & 2047;
    }
}

// Transpose-gather: per (group, 64-hw tile): coalesced read, LDS transpose
// (xor-swizzled), per-selected-column l2-normalize + write [dest][c] rows.
// groups 0..23 = refs (bn), 24..31 = feat (b). Refs also write f16 tiles
// laid out for 16x16x32 MFMA B-frags:
//   tile (32 cols x 256 K): byte = kstep*2048 + ct2*1024 + (khigh*16+c16)*16 + j*2
//   holds B[col=ct2*16+c16][k=kstep*32+khigh*8+j]
__global__ __launch_bounds__(256) void gather_kernel(
    const float* __restrict__ feat, const float* __restrict__ refs,
    const int* __restrict__ pindex, const int* __restrict__ inv,
    float* __restrict__ A_T, float* __restrict__ B_T,
    unsigned char* __restrict__ Btiles)
{
    int tileh = blockIdx.x & 63;
    int g = blockIdx.x >> 6;
    int isRef = (g < 24);
    const float* src;
    int b;
    if (isRef){
        b = g / 3; int r0 = g - b*3; int iv = *pindex;
        int rn = (r0 < iv) ? r0 : r0 + 1;
        src = refs + ((size_t)(b*4 + rn)) * Cp * HWp;
    } else {
        b = g - 24;
        src = feat + (size_t)b * Cp * HWp;
    }
    __shared__ float lds[64 * 256];       // [hw][c], xor-swizzled, 64KB
    int tid = threadIdx.x, hwl = tid & 63, cg = tid >> 6;
    int hw0 = tileh * 64;
    const float* sp = src + hw0 + hwl;
    int swz = (hwl & 7) << 3;
    float* lrow = lds + hwl * 256;
    #pragma unroll
    for (int i = 0; i < 16; i++){
        int c0 = cg * 64 + i * 4;
        float x0 = sp[(size_t)(c0 + 0) * HWp];
        float x1 = sp[(size_t)(c0 + 1) * HWp];
        float x2 = sp[(size_t)(c0 + 2) * HWp];
        float x3 = sp[(size_t)(c0 + 3) * HWp];
        *(float4*)(lrow + (c0 ^ swz)) = make_float4(x0, x1, x2, x3);
    }
    __syncthreads();
    int w = cg, lane = tid & 63;
    const int* invg = inv + g * 4096 + hw0;
    for (int h = w * 16; h < w * 16 + 16; h++){
        int dest = invg[h];
        if (dest < 0) continue;
        float4 v = *(float4*)(lds + h * 256 + ((lane * 4) ^ ((h & 7) << 3)));
        float ssq = v.x*v.x + v.y*v.y + v.z*v.z + v.w*v.w;
        #pragma unroll
        for (int off = 1; off < 64; off <<= 1) ssq += __shfl_xor(ssq, off, 64);
        float dn = fmaxf(sqrtf(ssq), 1e-12f);
        v.x /= dn; v.y /= dn; v.z /= dn; v.w /= dn;
        if (isRef){
            size_t row = ((size_t)g * Lp + dest) * Cp;
            *(float4*)(B_T + row + lane * 4) = v;
            // lane holds k = lane*4 + m (m=0..3):
            //   kstep = lane>>3, khigh = (lane>>1)&3, j = 4*(lane&1)+m
            unsigned char* tb = Btiles + ((size_t)g * 64 + (dest >> 5)) * 16384;
            int nn = dest & 31;
            int ct2 = nn >> 4, c16 = nn & 15;
            int byteoff = (lane >> 3) * 2048 + ct2 * 1024
                        + (((lane >> 1) & 3) * 16 + c16) * 16 + (lane & 1) * 8;
            ushort4 hv;
            hv.x = f16bits(v.x); hv.y = f16bits(v.y);
            hv.z = f16bits(v.z); hv.w = f16bits(v.w);
            *(ushort4*)(tb + byteoff) = hv;
        } else {
            size_t row = ((size_t)b * Lp + dest) * Cp;
            *(float4*)(A_T + row + lane * 4) = v;
        }
    }
}

__device__ __forceinline__ void stageB(const unsigned char* g, unsigned char* l){
    #pragma unroll
    for (int p = 0; p < 4; p++)
        __builtin_amdgcn_global_load_lds(
            (const __attribute__((address_space(1))) void*)(g + p*1024),
            (__attribute__((address_space(3))) void*)(l + p*1024),
            16, 0, 0);
}

__device__ __forceinline__ void top2upd(unsigned &p1, unsigned &p2, unsigned u){
    unsigned lo = min(p1, u);
    p1 = max(p1, u);
    p2 = max(p2, lo);
}

// fp16 A-2-plane (regs) x B-1-plane (LDS) MFMA GEMM, 16x16x32, fused packed
// top-2 over a 512-col chunk. Block: 256 thr (4 waves), 64 rows, 16 col-tiles.
__global__ __launch_bounds__(256, 3) void gemm_mfma_kernel(
    const float* __restrict__ A_T, const unsigned char* __restrict__ Btiles,
    unsigned int* __restrict__ ppk)
{
    int bid = blockIdx.x;
    int rowgrp = bid & 31;                 // innermost: share Btiles in L2
    int chunk = (bid >> 5) % 12;
    int b = bid / 384;
    int n = chunk >> 2, c4 = chunk & 3;
    int bn = b*3 + n;
    int tid = threadIdx.x, lane = tid & 63, w = tid >> 6;
    int l15 = lane & 15, lg = lane >> 4;   // lg in 0..3

    __shared__ unsigned char bufs[2][16384];

    // ---- A fragments: fp32 row -> fp16 hi/lo planes (8 ksteps) ----
    int row = rowgrp*64 + w*16 + l15;
    const float* Arow = A_T + ((size_t)b*Lp + row)*Cp + lg*8;
    union U8 { _Float16 h[8]; f16x8 v; };
    U8 AH[8], AL[8];
    #pragma unroll
    for (int ks = 0; ks < 8; ks++){
        float4 fa = *(const float4*)(Arow + ks*32);
        float4 fb = *(const float4*)(Arow + ks*32 + 4);
        float xs[8] = {fa.x, fa.y, fa.z, fa.w, fb.x, fb.y, fb.z, fb.w};
        #pragma unroll
        for (int jj = 0; jj < 8; jj++){
            _Float16 h = (_Float16)xs[jj];
            AH[ks].h[jj] = h;
            AL[ks].h[jj] = (_Float16)(xs[jj] - (float)h);
        }
    }

    // packed top-2 per (ct2, r): 8 sets
    unsigned p1[8], p2[8];
    #pragma unroll
    for (int s = 0; s < 8; s++){ p1[s] = 0u; p2[s] = 0u; }

    const unsigned char* tbase0 = Btiles + ((size_t)bn*64 + c4*16) * 16384;
    stageB(tbase0 + w*4096 + lane*16, &bufs[0][w*4096]);

    #pragma unroll 1
    for (int t = 0; t < 16; t++){
        if (t < 15){
            stageB(tbase0 + (size_t)(t+1)*16384 + w*4096 + lane*16, &bufs[(t+1)&1][w*4096]);
            asm volatile("s_waitcnt vmcnt(4)" ::: "memory");
        } else {
            asm volatile("s_waitcnt vmcnt(0)" ::: "memory");
        }
        __builtin_amdgcn_s_barrier();

        const unsigned char* bp = bufs[t & 1];
        f32x4 ah0 = {0.f,0.f,0.f,0.f}, al0 = {0.f,0.f,0.f,0.f};
        f32x4 ah1 = {0.f,0.f,0.f,0.f}, al1 = {0.f,0.f,0.f,0.f};
        #pragma unroll
        for (int ks = 0; ks < 8; ks++){
            f16x8 b0 = *(const f16x8*)(bp + ks*2048 + lane*16);
            f16x8 b1 = *(const f16x8*)(bp + ks*2048 + 1024 + lane*16);
            ah0 = __builtin_amdgcn_mfma_f32_16x16x32_f16(AH[ks].v, b0, ah0, 0, 0, 0);
            al0 = __builtin_amdgcn_mfma_f32_16x16x32_f16(AL[ks].v, b0, al0, 0, 0, 0);
            ah1 = __builtin_amdgcn_mfma_f32_16x16x32_f16(AH[ks].v, b1, ah1, 0, 0, 0);
            al1 = __builtin_amdgcn_mfma_f32_16x16x32_f16(AL[ks].v, b1, al1, 0, 0, 0);
        }
        __builtin_amdgcn_s_barrier();

        // pack & top-2; C/D: col = lane&15, row = (lane>>4)*4 + r
        unsigned ci0 = (unsigned)(511 - (t*32 + l15));
        unsigned ci1 = ci0 - 16;
        #pragma unroll
        for (int r = 0; r < 4; r++){
            float v0 = ah0[r] + al0[r];
            unsigned u0 = (__float_as_uint(v0 + 2.0f) & 0xFFFFFE00u) | ci0;
            top2upd(p1[r], p2[r], u0);
            float v1 = ah1[r] + al1[r];
            unsigned u1 = (__float_as_uint(v1 + 2.0f) & 0xFFFFFE00u) | ci1;
            top2upd(p1[4+r], p2[4+r], u1);
        }
    }

    // merge ct2 pair per r, then across 16-lane group
    #pragma unroll
    for (int r = 0; r < 4; r++){
        unsigned q1 = max(p1[r], p1[4+r]);
        unsigned q2 = max(min(p1[r], p1[4+r]), max(p2[r], p2[4+r]));
        #pragma unroll
        for (int off = 1; off < 16; off <<= 1){
            unsigned o1 = (unsigned)__shfl_xor((int)q1, off, 64);
            unsigned o2 = (unsigned)__shfl_xor((int)q2, off, 64);
            unsigned m1 = max(q1, o1);
            unsigned m2 = max(min(q1, o1), max(q2, o2));
            q1 = m1; q2 = m2;
        }
        if (l15 == 0){
            int row_local = lg*4 + r;   // 0..15
            size_t grow = (size_t)bn*Lp + rowgrp*64 + w*16 + row_local;
            size_t slot = grow*4 + c4;
            ppk[slot*2 + 0] = q1;
            ppk[slot*2 + 1] = q2;
        }
    }
}

__global__ void reset_kernel(int* count){ *count = 0; }

__global__ void combine_kernel(const unsigned int* __restrict__ ppk,
                               int* __restrict__ best, int* __restrict__ cand2,
                               float* __restrict__ outF, const int* __restrict__ baseIdx,
                               int* __restrict__ count, int* __restrict__ list)
{
    int gid = blockIdx.x * blockDim.x + threadIdx.x;
    if (gid < NROWS){
        unsigned V1 = 0u, V2 = 0u; int X1 = 0, X2 = 0;
        #pragma unroll
        for (int ch = 0; ch < 4; ch++){
            unsigned u1 = ppk[((size_t)gid*4 + ch)*2 + 0];
            unsigned u2 = ppk[((size_t)gid*4 + ch)*2 + 1];
            unsigned vb1 = u1 & 0xFFFFFE00u; int c1 = ch*512 + 511 - (int)(u1 & 511u);
            unsigned vb2 = u2 & 0xFFFFFE00u; int c2 = ch*512 + 511 - (int)(u2 & 511u);
            if (vb1 > V1 || (vb1 == V1 && c1 < X1)){
                V2 = V1; X2 = X1; V1 = vb1; X1 = c1;
            } else if (vb1 > V2 || (vb1 == V2 && c1 < X2)){
                V2 = vb1; X2 = c1;
            }
            // u2 <= u1 in packed order, so it only contends for second place
            if (vb2 > V2 || (vb2 == V2 && c2 < X2)){ V2 = vb2; X2 = c2; }
        }
        best[gid] = X1; cand2[gid] = X2;
        outF[OUT_REF_OFF + gid] = (float)X1;
        if (__uint_as_float(V1) - __uint_as_float(V2) < 3.6e-4f){
            int s = atomicAdd(count, 1);
            if (s < NROWS) list[s] = gid;
        }
    }
    if (gid < Bp*Lp) outF[OUT_BASE_OFF + gid] = (float)baseIdx[gid];
}

// fp64 re-decision for ambiguous rows from stored normalized fp32 (coalesced).
__global__ void refine_kernel(const float* __restrict__ A_T, const float* __restrict__ B_T,
                              const int* __restrict__ count, const int* __restrict__ list,
                              int* __restrict__ best, const int* __restrict__ cand2,
                              float* __restrict__ outF)
{
    int nf = *count; if (nf > NROWS) nf = NROWS;
    int lane = threadIdx.x & 63;
    for (int it = blockIdx.x; it < nf; it += gridDim.x){
        int gid = list[it];
        int bn = gid >> 11, l = gid & 2047;
        int b = bn / 3;
        int i1 = best[gid], i2 = cand2[gid];
        const float* ar  = A_T + ((size_t)b*Lp + l) * Cp;
        const float* b1r = B_T + ((size_t)bn*Lp + i1) * Cp;
        const float* b2r = B_T + ((size_t)bn*Lp + i2) * Cp;
        double d1 = 0.0, d2 = 0.0;
        #pragma unroll
        for (int j = 0; j < 4; j++){
            double a = (double)ar[lane*4 + j];
            d1 += a * (double)b1r[lane*4 + j];
            d2 += a * (double)b2r[lane*4 + j];
        }
        #pragma unroll
        for (int off = 1; off < 64; off <<= 1){
            d1 += __shfl_xor(d1, off, 64);
            d2 += __shfl_xor(d2, off, 64);
        }
        if (lane == 0){
            int ix = (d2 > d1 || (d2 == d1 && i2 < i1)) ? i2 : i1;
            best[gid] = ix;
            outF[OUT_REF_OFF + gid] = (float)ix;
        }
    }
}

// Tile-based fuse: load feat tile -> LDS (rotation layout, conflict-free),
// overwrite selected columns with fused values, write full tile coalesced.
__global__ __launch_bounds__(256) void fuse_tile_kernel(
    const float* __restrict__ feat, const float* __restrict__ B_T,
    const int* __restrict__ best, const int* __restrict__ inv,
    const float* __restrict__ sim, const int* __restrict__ pindex,
    float* __restrict__ out)
{
    int tileh = blockIdx.x & 63;
    int b = blockIdx.x >> 6;
    int hw0 = tileh * 64;
    __shared__ float lds[256 * 64];       // addr(c,hw) = c*64 + ((hw + c) & 63)
    int tid = threadIdx.x, hwl = tid & 63, cg = tid >> 6;
    const float* fb = feat + (size_t)b * Cp * HWp + hw0 + hwl;
    #pragma unroll 4
    for (int i = 0; i < 64; i++){
        int c = cg * 64 + i;
        lds[c * 64 + ((hwl + c) & 63)] = fb[(size_t)c * HWp];
    }
    __syncthreads();
    int iv = *pindex;
    float bs  = sim[b*4 + iv];
    float rs0 = sim[b*4 + ((0 < iv) ? 0 : 1)];
    float rs1 = sim[b*4 + ((1 < iv) ? 1 : 2)];
    float rs2 = sim[b*4 + ((2 < iv) ? 2 : 3)];
    int w = cg, lane = tid & 63;
    const int* invg = inv + (24 + b) * 4096 + hw0;
    for (int h = w * 16; h < w * 16 + 16; h++){
        int dest = invg[h];
        if (dest < 0) continue;
        int b0 = best[(b*3 + 0)*Lp + dest];
        int b1 = best[(b*3 + 1)*Lp + dest];
        int b2 = best[(b*3 + 2)*Lp + dest];
        const float* r0 = B_T + ((size_t)(b*3 + 0)*Lp + b0) * Cp;
        const float* r1 = B_T + ((size_t)(b*3 + 1)*Lp + b1) * Cp;
        const float* r2 = B_T + ((size_t)(b*3 + 2)*Lp + b2) * Cp;
        #pragma unroll
        for (int j = 0; j < 4; j++){
            int c = lane + j * 64;
            int la = c * 64 + ((h + c) & 63);
            float base = lds[la];
            lds[la] = bs*base + rs0*r0[c] + rs1*r1[c] + rs2*r2[c];
        }
    }
    __syncthreads();
    float* ob = out + (size_t)b * Cp * HWp + hw0 + hwl;
    #pragma unroll 4
    for (int i = 0; i < 64; i++){
        int c = cg * 64 + i;
        ob[(size_t)c * HWp] = lds[c * 64 + ((hwl + c) & 63)];
    }
}

extern "C" void kernel_launch(void* const* d_in, const int* in_sizes, int n_in,
                              void* d_out, int out_size, void* d_ws, size_t ws_size,
                              hipStream_t stream)
{
    const float* feat    = (const float*)d_in[0];
    const float* refs    = (const float*)d_in[1];
    const float* sim     = (const float*)d_in[2];
    const int*   baseIdx = (const int*)d_in[3];
    const int*   refIdxI = (const int*)d_in[4];
    const int*   pindex  = (const int*)d_in[5];
    float* out = (float*)d_out;
    unsigned char* ws = (unsigned char*)d_ws;

    float* A_T   = (float*)(ws + OFF_AT);
    float* B_T   = (float*)(ws + OFF_BT);
    unsigned char* Btiles = ws + OFF_BSPL;
    unsigned int* ppk = (unsigned int*)(ws + OFF_PVAL);
    int* best  = (int*)(ws + OFF_BEST);
    int* cand2 = (int*)(ws + OFF_CAND2);
    int* count = (int*)(ws + OFF_COUNT);
    int* list  = (int*)(ws + OFF_LIST);
    int* inv   = (int*)(ws + OFF_INV);

    init_inv_kernel<<<128, 256, 0, stream>>>((int4*)inv);
    scatter_inv_kernel<<<256, 256, 0, stream>>>(refIdxI, baseIdx, inv);
    gather_kernel<<<2048, 256, 0, stream>>>(feat, refs, pindex, inv, A_T, B_T, Btiles);
    gemm_mfma_kernel<<<3072, 256, 0, stream>>>(A_T, Btiles, ppk);
    reset_kernel<<<1, 1, 0, stream>>>(count);
    combine_kernel<<<192, 256, 0, stream>>>(ppk, best, cand2, out, baseIdx, count, list);
    refine_kernel<<<512, 64, 0, stream>>>(A_T, B_T, count, list, best, cand2, out);
    fuse_tile_kernel<<<512, 256, 0, stream>>>(feat, B_T, best, inv, sim, pindex, out);
}

// Round 6
// 206.666 us; speedup vs baseline: 5.7220x; 1.0200x over previous
//
#include <hip/hip_runtime.h>
#include <math.h>

#define HWp 4096
#define Cp 256
#define Lp 2048
#define Np 3
#define Bp 8

#define OUT_FEAT_N 8388608      // 8*256*4096
#define OUT_BASE_OFF 8388608
#define OUT_REF_OFF 8404992     // + 8*2048
#define NROWS 49152             // 24*2048

// ---- ws byte offsets ----
#define OFF_AT    ((size_t)0)              // A_T fp32 [8][2048][256]   = 16,777,216 B
#define OFF_BT    ((size_t)16777216)       // B_T fp32 [24][2048][256]  = 50,331,648 B
#define OFF_BSPL  ((size_t)67108864)       // Btiles [24][64][16384]    = 25,165,824 B
#define OFF_PVAL  ((size_t)117440512)      // ppk: 49152*4*2*4 = 1,572,864
#define OFF_BEST  ((size_t)119799808)      // 196,608
#define OFF_CAND2 ((size_t)119996416)      // 196,608
#define OFF_COUNT ((size_t)120193024)      // 4 (pad to 256)
#define OFF_LIST  ((size_t)120193280)      // 196,608
#define OFF_INV   ((size_t)120389888)      // 32*4096*4 = 524,288

typedef _Float16 f16x8 __attribute__((ext_vector_type(8)));
typedef float f32x4 __attribute__((ext_vector_type(4)));

__device__ __forceinline__ unsigned short f16bits(float x){
    union { _Float16 h; unsigned short s; } u;
    u.h = (_Float16)x;
    return u.s;
}

__global__ void init_inv_kernel(int4* __restrict__ inv4){
    int tid = blockIdx.x * blockDim.x + threadIdx.x;   // 32768 int4
    if (tid < 32768) inv4[tid] = make_int4(-1, -1, -1, -1);
}

__global__ void scatter_inv_kernel(const int* __restrict__ refIdxI,
                                   const int* __restrict__ baseIdx,
                                   int* __restrict__ inv){
    int tid = blockIdx.x * blockDim.x + threadIdx.x;   // 65536
    if (tid < NROWS){
        int g = tid >> 11;
        inv[g*4096 + refIdxI[tid]] = tid & 2047;
    } else if (tid < NROWS + Bp*Lp){
        int t = tid - NROWS;
        int b = t >> 11;
        inv[(24 + b)*4096 + baseIdx[t]] = t & 2047;
    }
}

// Transpose-gather: per (group, 64-hw tile): coalesced read, LDS transpose
// (xor-swizzled), per-selected-column l2-normalize + write [dest][c] rows.
// groups 0..23 = refs (bn), 24..31 = feat (b). Refs also write f16 tiles
// laid out for 16x16x32 MFMA B-frags:
//   tile (32 cols x 256 K): byte = kstep*2048 + ct2*1024 + (khigh*16+c16)*16 + j*2
//   holds B[col=ct2*16+c16][k=kstep*32+khigh*8+j]
__global__ __launch_bounds__(256) void gather_kernel(
    const float* __restrict__ feat, const float* __restrict__ refs,
    const int* __restrict__ pindex, const int* __restrict__ inv,
    float* __restrict__ A_T, float* __restrict__ B_T,
    unsigned char* __restrict__ Btiles)
{
    int tileh = blockIdx.x & 63;
    int g = blockIdx.x >> 6;
    int isRef = (g < 24);
    const float* src;
    int b;
    if (isRef){
        b = g / 3; int r0 = g - b*3; int iv = *pindex;
        int rn = (r0 < iv) ? r0 : r0 + 1;
        src = refs + ((size_t)(b*4 + rn)) * Cp * HWp;
    } else {
        b = g - 24;
        src = feat + (size_t)b * Cp * HWp;
    }
    __shared__ float lds[64 * 256];       // [hw][c], xor-swizzled, 64KB
    int tid = threadIdx.x, hwl = tid & 63, cg = tid >> 6;
    int hw0 = tileh * 64;
    const float* sp = src + hw0 + hwl;
    int swz = (hwl & 7) << 3;
    float* lrow = lds + hwl * 256;
    #pragma unroll
    for (int i = 0; i < 16; i++){
        int c0 = cg * 64 + i * 4;
        float x0 = sp[(size_t)(c0 + 0) * HWp];
        float x1 = sp[(size_t)(c0 + 1) * HWp];
        float x2 = sp[(size_t)(c0 + 2) * HWp];
        float x3 = sp[(size_t)(c0 + 3) * HWp];
        *(float4*)(lrow + (c0 ^ swz)) = make_float4(x0, x1, x2, x3);
    }
    __syncthreads();
    int w = cg, lane = tid & 63;
    const int* invg = inv + g * 4096 + hw0;
    for (int h = w * 16; h < w * 16 + 16; h++){
        int dest = invg[h];
        if (dest < 0) continue;
        float4 v = *(float4*)(lds + h * 256 + ((lane * 4) ^ ((h & 7) << 3)));
        float ssq = v.x*v.x + v.y*v.y + v.z*v.z + v.w*v.w;
        #pragma unroll
        for (int off = 1; off < 64; off <<= 1) ssq += __shfl_xor(ssq, off, 64);
        float dn = fmaxf(sqrtf(ssq), 1e-12f);
        v.x /= dn; v.y /= dn; v.z /= dn; v.w /= dn;
        if (isRef){
            size_t row = ((size_t)g * Lp + dest) * Cp;
            *(float4*)(B_T + row + lane * 4) = v;
            // lane holds k = lane*4 + m (m=0..3):
            //   kstep = lane>>3, khigh = (lane>>1)&3, j = 4*(lane&1)+m
            unsigned char* tb = Btiles + ((size_t)g * 64 + (dest >> 5)) * 16384;
            int nn = dest & 31;
            int ct2 = nn >> 4, c16 = nn & 15;
            int byteoff = (lane >> 3) * 2048 + ct2 * 1024
                        + (((lane >> 1) & 3) * 16 + c16) * 16 + (lane & 1) * 8;
            ushort4 hv;
            hv.x = f16bits(v.x); hv.y = f16bits(v.y);
            hv.z = f16bits(v.z); hv.w = f16bits(v.w);
            *(ushort4*)(tb + byteoff) = hv;
        } else {
            size_t row = ((size_t)b * Lp + dest) * Cp;
            *(float4*)(A_T + row + lane * 4) = v;
        }
    }
}

__device__ __forceinline__ void stageB(const unsigned char* g, unsigned char* l){
    #pragma unroll
    for (int p = 0; p < 4; p++)
        __builtin_amdgcn_global_load_lds(
            (const __attribute__((address_space(1))) void*)(g + p*1024),
            (__attribute__((address_space(3))) void*)(l + p*1024),
            16, 0, 0);
}

__device__ __forceinline__ void top2upd(unsigned &p1, unsigned &p2, unsigned u){
    unsigned lo = min(p1, u);
    p1 = max(p1, u);
    p2 = max(p2, lo);
}

// fp16 A-2-plane (regs) x B-1-plane (LDS) MFMA GEMM, 16x16x32, 2 rowsets/wave
// (M_w=32: each B-frag feeds 8 MFMAs -> 256 B/MFMA LDS demand), fused packed
// top-2 over a 512-col chunk. Block: 256 thr (4 waves), 128 rows, 16 col-tiles.
__global__ __launch_bounds__(256, 2) void gemm_mfma_kernel(
    const float* __restrict__ A_T, const unsigned char* __restrict__ Btiles,
    unsigned int* __restrict__ ppk)
{
    int bid = blockIdx.x;
    int rowgrp = bid & 15;                 // innermost: share Btiles in L2
    int chunk = (bid >> 4) % 12;
    int b = bid / 192;
    int n = chunk >> 2, c4 = chunk & 3;
    int bn = b*3 + n;
    int tid = threadIdx.x, lane = tid & 63, w = tid >> 6;
    int l15 = lane & 15, lg = lane >> 4;   // lg in 0..3

    __shared__ unsigned char bufs[2][16384];

    // ---- A fragments: fp32 rows -> fp16 hi/lo planes, 2 rowsets x 8 ksteps ----
    int row0 = rowgrp*128 + w*16 + l15;
    const float* Arow0 = A_T + ((size_t)b*Lp + row0)*Cp + lg*8;
    const float* Arow1 = Arow0 + (size_t)64*Cp;
    union U8 { _Float16 h[8]; f16x8 v; };
    U8 AH0[8], AL0[8], AH1[8], AL1[8];
    #pragma unroll
    for (int ks = 0; ks < 8; ks++){
        float4 fa = *(const float4*)(Arow0 + ks*32);
        float4 fb = *(const float4*)(Arow0 + ks*32 + 4);
        float xs[8] = {fa.x, fa.y, fa.z, fa.w, fb.x, fb.y, fb.z, fb.w};
        #pragma unroll
        for (int jj = 0; jj < 8; jj++){
            _Float16 h = (_Float16)xs[jj];
            AH0[ks].h[jj] = h;
            AL0[ks].h[jj] = (_Float16)(xs[jj] - (float)h);
        }
        float4 fc = *(const float4*)(Arow1 + ks*32);
        float4 fd = *(const float4*)(Arow1 + ks*32 + 4);
        float ys[8] = {fc.x, fc.y, fc.z, fc.w, fd.x, fd.y, fd.z, fd.w};
        #pragma unroll
        for (int jj = 0; jj < 8; jj++){
            _Float16 h = (_Float16)ys[jj];
            AH1[ks].h[jj] = h;
            AL1[ks].h[jj] = (_Float16)(ys[jj] - (float)h);
        }
    }

    // packed top-2 per (rowset, ct2, r): 16 sets
    unsigned p1[16], p2[16];
    #pragma unroll
    for (int s = 0; s < 16; s++){ p1[s] = 0u; p2[s] = 0u; }

    const unsigned char* tbase0 = Btiles + ((size_t)bn*64 + c4*16) * 16384;
    stageB(tbase0 + w*4096 + lane*16, &bufs[0][w*4096]);

    #pragma unroll 1
    for (int t = 0; t < 16; t++){
        if (t < 15){
            stageB(tbase0 + (size_t)(t+1)*16384 + w*4096 + lane*16, &bufs[(t+1)&1][w*4096]);
            asm volatile("s_waitcnt vmcnt(4)" ::: "memory");
        } else {
            asm volatile("s_waitcnt vmcnt(0)" ::: "memory");
        }
        __builtin_amdgcn_s_barrier();

        const unsigned char* bp = bufs[t & 1];
        f32x4 h00 = {0.f,0.f,0.f,0.f}, l00 = {0.f,0.f,0.f,0.f};
        f32x4 h01 = {0.f,0.f,0.f,0.f}, l01 = {0.f,0.f,0.f,0.f};
        f32x4 h10 = {0.f,0.f,0.f,0.f}, l10 = {0.f,0.f,0.f,0.f};
        f32x4 h11 = {0.f,0.f,0.f,0.f}, l11 = {0.f,0.f,0.f,0.f};
        #pragma unroll
        for (int ks = 0; ks < 8; ks++){
            f16x8 b0 = *(const f16x8*)(bp + ks*2048 + lane*16);
            f16x8 b1 = *(const f16x8*)(bp + ks*2048 + 1024 + lane*16);
            h00 = __builtin_amdgcn_mfma_f32_16x16x32_f16(AH0[ks].v, b0, h00, 0, 0, 0);
            l00 = __builtin_amdgcn_mfma_f32_16x16x32_f16(AL0[ks].v, b0, l00, 0, 0, 0);
            h01 = __builtin_amdgcn_mfma_f32_16x16x32_f16(AH0[ks].v, b1, h01, 0, 0, 0);
            l01 = __builtin_amdgcn_mfma_f32_16x16x32_f16(AL0[ks].v, b1, l01, 0, 0, 0);
            h10 = __builtin_amdgcn_mfma_f32_16x16x32_f16(AH1[ks].v, b0, h10, 0, 0, 0);
            l10 = __builtin_amdgcn_mfma_f32_16x16x32_f16(AL1[ks].v, b0, l10, 0, 0, 0);
            h11 = __builtin_amdgcn_mfma_f32_16x16x32_f16(AH1[ks].v, b1, h11, 0, 0, 0);
            l11 = __builtin_amdgcn_mfma_f32_16x16x32_f16(AL1[ks].v, b1, l11, 0, 0, 0);
        }
        __builtin_amdgcn_s_barrier();

        // pack & top-2; C/D: col = lane&15, row = (lane>>4)*4 + r
        unsigned ci0 = (unsigned)(511 - (t*32 + l15));
        unsigned ci1 = ci0 - 16;
        #pragma unroll
        for (int r = 0; r < 4; r++){
            float v00 = h00[r] + l00[r];
            top2upd(p1[r],    p2[r],    (__float_as_uint(v00 + 2.0f) & 0xFFFFFE00u) | ci0);
            float v01 = h01[r] + l01[r];
            top2upd(p1[4+r],  p2[4+r],  (__float_as_uint(v01 + 2.0f) & 0xFFFFFE00u) | ci1);
            float v10 = h10[r] + l10[r];
            top2upd(p1[8+r],  p2[8+r],  (__float_as_uint(v10 + 2.0f) & 0xFFFFFE00u) | ci0);
            float v11 = h11[r] + l11[r];
            top2upd(p1[12+r], p2[12+r], (__float_as_uint(v11 + 2.0f) & 0xFFFFFE00u) | ci1);
        }
    }

    // merge ct2 pair per (rowset, r), then across 16-lane group
    #pragma unroll
    for (int rs = 0; rs < 2; rs++){
        #pragma unroll
        for (int r = 0; r < 4; r++){
            unsigned a1 = p1[rs*8 + r],     b1v = p1[rs*8 + 4 + r];
            unsigned a2 = p2[rs*8 + r],     b2v = p2[rs*8 + 4 + r];
            unsigned q1 = max(a1, b1v);
            unsigned q2 = max(min(a1, b1v), max(a2, b2v));
            #pragma unroll
            for (int off = 1; off < 16; off <<= 1){
                unsigned o1 = (unsigned)__shfl_xor((int)q1, off, 64);
                unsigned o2 = (unsigned)__shfl_xor((int)q2, off, 64);
                unsigned m1 = max(q1, o1);
                unsigned m2 = max(min(q1, o1), max(q2, o2));
                q1 = m1; q2 = m2;
            }
            if (l15 == 0){
                size_t grow = (size_t)bn*Lp + rowgrp*128 + rs*64 + w*16 + lg*4 + r;
                size_t slot = grow*4 + c4;
                ppk[slot*2 + 0] = q1;
                ppk[slot*2 + 1] = q2;
            }
        }
    }
}

__global__ void reset_kernel(int* count){ *count = 0; }

__global__ void combine_kernel(const unsigned int* __restrict__ ppk,
                               int* __restrict__ best, int* __restrict__ cand2,
                               float* __restrict__ outF, const int* __restrict__ baseIdx,
                               int* __restrict__ count, int* __restrict__ list)
{
    int gid = blockIdx.x * blockDim.x + threadIdx.x;
    if (gid < NROWS){
        unsigned V1 = 0u, V2 = 0u; int X1 = 0, X2 = 0;
        #pragma unroll
        for (int ch = 0; ch < 4; ch++){
            unsigned u1 = ppk[((size_t)gid*4 + ch)*2 + 0];
            unsigned u2 = ppk[((size_t)gid*4 + ch)*2 + 1];
            unsigned vb1 = u1 & 0xFFFFFE00u; int c1 = ch*512 + 511 - (int)(u1 & 511u);
            unsigned vb2 = u2 & 0xFFFFFE00u; int c2 = ch*512 + 511 - (int)(u2 & 511u);
            if (vb1 > V1 || (vb1 == V1 && c1 < X1)){
                V2 = V1; X2 = X1; V1 = vb1; X1 = c1;
            } else if (vb1 > V2 || (vb1 == V2 && c1 < X2)){
                V2 = vb1; X2 = c1;
            }
            // u2 <= u1 in packed order, so it only contends for second place
            if (vb2 > V2 || (vb2 == V2 && c2 < X2)){ V2 = vb2; X2 = c2; }
        }
        best[gid] = X1; cand2[gid] = X2;
        outF[OUT_REF_OFF + gid] = (float)X1;
        if (__uint_as_float(V1) - __uint_as_float(V2) < 3.6e-4f){
            int s = atomicAdd(count, 1);
            if (s < NROWS) list[s] = gid;
        }
    }
    if (gid < Bp*Lp) outF[OUT_BASE_OFF + gid] = (float)baseIdx[gid];
}

// fp64 re-decision for ambiguous rows from stored normalized fp32 (coalesced).
__global__ void refine_kernel(const float* __restrict__ A_T, const float* __restrict__ B_T,
                              const int* __restrict__ count, const int* __restrict__ list,
                              int* __restrict__ best, const int* __restrict__ cand2,
                              float* __restrict__ outF)
{
    int nf = *count; if (nf > NROWS) nf = NROWS;
    int lane = threadIdx.x & 63;
    for (int it = blockIdx.x; it < nf; it += gridDim.x){
        int gid = list[it];
        int bn = gid >> 11, l = gid & 2047;
        int b = bn / 3;
        int i1 = best[gid], i2 = cand2[gid];
        const float* ar  = A_T + ((size_t)b*Lp + l) * Cp;
        const float* b1r = B_T + ((size_t)bn*Lp + i1) * Cp;
        const float* b2r = B_T + ((size_t)bn*Lp + i2) * Cp;
        double d1 = 0.0, d2 = 0.0;
        #pragma unroll
        for (int j = 0; j < 4; j++){
            double a = (double)ar[lane*4 + j];
            d1 += a * (double)b1r[lane*4 + j];
            d2 += a * (double)b2r[lane*4 + j];
        }
        #pragma unroll
        for (int off = 1; off < 64; off <<= 1){
            d1 += __shfl_xor(d1, off, 64);
            d2 += __shfl_xor(d2, off, 64);
        }
        if (lane == 0){
            int ix = (d2 > d1 || (d2 == d1 && i2 < i1)) ? i2 : i1;
            best[gid] = ix;
            outF[OUT_REF_OFF + gid] = (float)ix;
        }
    }
}

// Tile-based fuse: load feat tile -> LDS (rotation layout, conflict-free),
// overwrite selected columns with fused values, write full tile coalesced.
__global__ __launch_bounds__(256) void fuse_tile_kernel(
    const float* __restrict__ feat, const float* __restrict__ B_T,
    const int* __restrict__ best, const int* __restrict__ inv,
    const float* __restrict__ sim, const int* __restrict__ pindex,
    float* __restrict__ out)
{
    int tileh = blockIdx.x & 63;
    int b = blockIdx.x >> 6;
    int hw0 = tileh * 64;
    __shared__ float lds[256 * 64];       // addr(c,hw) = c*64 + ((hw + c) & 63)
    int tid = threadIdx.x, hwl = tid & 63, cg = tid >> 6;
    const float* fb = feat + (size_t)b * Cp * HWp + hw0 + hwl;
    #pragma unroll 4
    for (int i = 0; i < 64; i++){
        int c = cg * 64 + i;
        lds[c * 64 + ((hwl + c) & 63)] = fb[(size_t)c * HWp];
    }
    __syncthreads();
    int iv = *pindex;
    float bs  = sim[b*4 + iv];
    float rs0 = sim[b*4 + ((0 < iv) ? 0 : 1)];
    float rs1 = sim[b*4 + ((1 < iv) ? 1 : 2)];
    float rs2 = sim[b*4 + ((2 < iv) ? 2 : 3)];
    int w = cg, lane = tid & 63;
    const int* invg = inv + (24 + b) * 4096 + hw0;
    for (int h = w * 16; h < w * 16 + 16; h++){
        int dest = invg[h];
        if (dest < 0) continue;
        int b0 = best[(b*3 + 0)*Lp + dest];
        int b1 = best[(b*3 + 1)*Lp + dest];
        int b2 = best[(b*3 + 2)*Lp + dest];
        const float* r0 = B_T + ((size_t)(b*3 + 0)*Lp + b0) * Cp;
        const float* r1 = B_T + ((size_t)(b*3 + 1)*Lp + b1) * Cp;
        const float* r2 = B_T + ((size_t)(b*3 + 2)*Lp + b2) * Cp;
        #pragma unroll
        for (int j = 0; j < 4; j++){
            int c = lane + j * 64;
            int la = c * 64 + ((h + c) & 63);
            float base = lds[la];
            lds[la] = bs*base + rs0*r0[c] + rs1*r1[c] + rs2*r2[c];
        }
    }
    __syncthreads();
    float* ob = out + (size_t)b * Cp * HWp + hw0 + hwl;
    #pragma unroll 4
    for (int i = 0; i < 64; i++){
        int c = cg * 64 + i;
        ob[(size_t)c * HWp] = lds[c * 64 + ((hwl + c) & 63)];
    }
}

extern "C" void kernel_launch(void* const* d_in, const int* in_sizes, int n_in,
                              void* d_out, int out_size, void* d_ws, size_t ws_size,
                              hipStream_t stream)
{
    const float* feat    = (const float*)d_in[0];
    const float* refs    = (const float*)d_in[1];
    const float* sim     = (const float*)d_in[2];
    const int*   baseIdx = (const int*)d_in[3];
    const int*   refIdxI = (const int*)d_in[4];
    const int*   pindex  = (const int*)d_in[5];
    float* out = (float*)d_out;
    unsigned char* ws = (unsigned char*)d_ws;

    float* A_T   = (float*)(ws + OFF_AT);
    float* B_T   = (float*)(ws + OFF_BT);
    unsigned char* Btiles = ws + OFF_BSPL;
    unsigned int* ppk = (unsigned int*)(ws + OFF_PVAL);
    int* best  = (int*)(ws + OFF_BEST);
    int* cand2 = (int*)(ws + OFF_CAND2);
    int* count = (int*)(ws + OFF_COUNT);
    int* list  = (int*)(ws + OFF_LIST);
    int* inv   = (int*)(ws + OFF_INV);

    init_inv_kernel<<<128, 256, 0, stream>>>((int4*)inv);
    scatter_inv_kernel<<<256, 256, 0, stream>>>(refIdxI, baseIdx, inv);
    gather_kernel<<<2048, 256, 0, stream>>>(feat, refs, pindex, inv, A_T, B_T, Btiles);
    gemm_mfma_kernel<<<1536, 256, 0, stream>>>(A_T, Btiles, ppk);
    reset_kernel<<<1, 1, 0, stream>>>(count);
    combine_kernel<<<192, 256, 0, stream>>>(ppk, best, cand2, out, baseIdx, count, list);
    refine_kernel<<<512, 64, 0, stream>>>(A_T, B_T, count, list, best, cand2, out);
    fuse_tile_kernel<<<512, 256, 0, stream>>>(feat, B_T, best, inv, sim, pindex, out);
}